// Round 4
// baseline (2986.630 us; speedup 1.0000x reference)
//
#include <hip/hip_runtime.h>
#include <hip/hip_bf16.h>

#define BB 16
#define SS 512
#define DM 256
#define NH 8
#define DKK 32
#define DVV 32
#define TQ 8

// workspace layout in float units
#define OFF_QP   0
#define OFF_KT   2097152
#define OFF_VB   4194304   // bf16 V [b,s,c]: 2097152 elems = 1048576 floats
#define OFF_VP2  5242880
#define OFF_CTX  5505024
#define OFF_CTX2 7602176
#define OFF_G    7864320   // bf16 g [b,q,k]: 4194304 elems = 2097152 floats
#define OFF_FLAG 9961472

#define SCALE 0.17677669529663687f

// ---------------------------------------------------------------------------
// K0: OR-reduce first 64K words of the mask into *acc (acc pre-zeroed).
__global__ void mask_or_kernel(const unsigned int* __restrict__ w,
                               unsigned int* __restrict__ acc) {
  __shared__ unsigned int sh[256];
  unsigned int a = 0;
  int base = blockIdx.x * 1024;
  for (int i = threadIdx.x; i < 1024; i += 256) a |= w[base + i];
  sh[threadIdx.x] = a;
  __syncthreads();
  for (int s = 128; s > 0; s >>= 1) {
    if (threadIdx.x < s) sh[threadIdx.x] |= sh[threadIdx.x + s];
    __syncthreads();
  }
  if (threadIdx.x == 0) atomicOr(acc, sh[0]);
}

// ---------------------------------------------------------------------------
// K1: projections. 512 threads: c = tid&255, row-half hf = tid>>8 (8 rows
// each), 16 rows per block -> grid 512 (2 blocks/CU).
__global__ __launch_bounds__(512) void proj_kernel(
    const float* __restrict__ inQ, const float* __restrict__ inK,
    const float* __restrict__ inV,
    const float* __restrict__ Wq, const float* __restrict__ Wk,
    const float* __restrict__ Wv, const float* __restrict__ Wv2,
    float* __restrict__ Qp, float* __restrict__ Kt,
    __hip_bfloat16* __restrict__ Vb, float* __restrict__ Vp2) {
  __shared__ float xs[16][257];
  const int tid = threadIdx.x;
  const int c = tid & 255;
  const int hf = tid >> 8;
  const int rbase = hf * 8;
  const int r0 = blockIdx.x * 16;
  float acc[8];

  // ---- Q ----
  for (int e = tid; e < 16 * DM; e += 512) {
    int r = e >> 8, i = e & 255;
    xs[r][i] = inQ[(r0 + r) * DM + i];
  }
  __syncthreads();
#pragma unroll
  for (int r = 0; r < 8; r++) acc[r] = 0.f;
  for (int i = 0; i < DM; i++) {
    float w = Wq[i * 256 + c];
#pragma unroll
    for (int r = 0; r < 8; r++) acc[r] += xs[rbase + r][i] * w;
  }
#pragma unroll
  for (int r = 0; r < 8; r++) Qp[(r0 + rbase + r) * 256 + c] = acc[r];
  __syncthreads();

  // ---- K (store transposed per head: Kt[(b*256+c)*512 + s]) ----
  for (int e = tid; e < 16 * DM; e += 512) {
    int r = e >> 8, i = e & 255;
    xs[r][i] = inK[(r0 + r) * DM + i];
  }
  __syncthreads();
#pragma unroll
  for (int r = 0; r < 8; r++) acc[r] = 0.f;
  for (int i = 0; i < DM; i++) {
    float w = Wk[i * 256 + c];
#pragma unroll
    for (int r = 0; r < 8; r++) acc[r] += xs[rbase + r][i] * w;
  }
#pragma unroll
  for (int r = 0; r < 8; r++) {
    int rg = r0 + rbase + r;
    int b = rg >> 9, sidx = rg & 511;
    Kt[(b * 256 + c) * 512 + sidx] = acc[r];
  }
  __syncthreads();

  // ---- V (bf16 row-major out) ----
  for (int e = tid; e < 16 * DM; e += 512) {
    int r = e >> 8, i = e & 255;
    xs[r][i] = inV[(r0 + r) * DM + i];
  }
  __syncthreads();
#pragma unroll
  for (int r = 0; r < 8; r++) acc[r] = 0.f;
  for (int i = 0; i < DM; i++) {
    float w = Wv[i * 256 + c];
#pragma unroll
    for (int r = 0; r < 8; r++) acc[r] += xs[rbase + r][i] * w;
  }
#pragma unroll
  for (int r = 0; r < 8; r++)
    Vb[(r0 + rbase + r) * 256 + c] = __float2bfloat16(acc[r]);

  // ---- V2 (reuse V rows in LDS): one (row, col) per thread ----
  {
    int c2 = tid & 31, rr = tid >> 5;  // rr 0..15
    float a = 0.f;
    for (int i = 0; i < DM; i++) a += xs[rr][i] * Wv2[i * 32 + c2];
    Vp2[(r0 + rr) * 32 + c2] = a;
  }
}

// ---------------------------------------------------------------------------
// K2: fused scores + softmax + gate + AV. 512 threads (8 waves = 8 heads),
// q-tile of 8. XCD-swizzled so each XCD sees only 2 batches (L2 reuse of
// Kt/Vb).
// CRITICAL: both kg loops are fully unrolled so every index into s[][] is a
// compile-time constant — a runtime kg demotes s[8][8] to scratch (HBM!),
// which was the 388 MB phantom WRITE_SIZE in rounds 1-3.
// No min-wave launch bound (forcing 4 waves/EU caps VGPR at 64 -> spill).
__global__ __launch_bounds__(512) void attn_kernel(
    const float* __restrict__ Qp, const float* __restrict__ Kt,
    const __hip_bfloat16* __restrict__ Vb, const void* __restrict__ mask,
    const float* __restrict__ matrix,
    const float* __restrict__ fulng, const float* __restrict__ fulnb,
    const float* __restrict__ fuw1, const float* __restrict__ fub1,
    const float* __restrict__ fuw2, const float* __restrict__ fub2,
    float* __restrict__ ctx, __hip_bfloat16* __restrict__ gws,
    const unsigned int* __restrict__ orv) {
  __shared__ float Qs[TQ][DM];              // 8 KB
  __shared__ float P[NH][TQ][64];           // 16 KB
  __shared__ float M1[TQ][64];              // 2 KB
  __shared__ __hip_bfloat16 Vs[64][256];    // 32 KB
  __shared__ float fup[85];

  const int tid = threadIdx.x;
  const int lane = tid & 63;
  const int h = tid >> 6;
  // XCD-aware swizzle: XCD = blockIdx % 8 (heuristic); give each XCD 2 b's.
  const int slot = blockIdx.x >> 3;
  const int b = ((blockIdx.x & 7) << 1) | (slot >> 6);
  const int q0 = (slot & 63) * TQ;

  for (int e = tid; e < TQ * DM; e += 512) {
    int q = e >> 8, i = e & 255;
    Qs[q][i] = Qp[((b << 9) + q0 + q) * 256 + i];
  }
  if (tid < 9) fup[tid] = fulng[tid];
  else if (tid < 18) fup[tid] = fulnb[tid - 9];
  else if (tid < 72) fup[tid] = fuw1[tid - 18];
  else if (tid < 78) fup[tid] = fub1[tid - 72];
  else if (tid < 84) fup[tid] = fuw2[tid - 78];
  else if (tid == 84) fup[tid] = fub2[0];
  const unsigned int rawor = *orv;
  const int flagv = (rawor <= 1u) ? 0 : ((rawor == 0x3F800000u) ? 2 : 1);
  __syncthreads();

  const int* mask_i = (const int*)mask;
  const unsigned char* mask_b = (const unsigned char*)mask;
  const float* mask_f = (const float*)mask;

  float s[TQ][8];

  // ---- phase 1: scores + mask (kg fully unrolled: s stays in VGPRs) ----
#pragma unroll
  for (int kg = 0; kg < 8; kg++) {
    int kglob = kg * 64 + lane;
    float kc[DKK];
#pragma unroll
    for (int d = 0; d < DKK; d++)
      kc[d] = Kt[(b * 256 + h * 32 + d) * 512 + kglob];
#pragma unroll
    for (int q = 0; q < TQ; q++) {
      float a = 0.f;
#pragma unroll
      for (int d = 0; d < DKK; d++) a += Qs[q][h * 32 + d] * kc[d];
      a *= SCALE;
      int midx = ((b * 8 + h) * 512 + q0 + q) * 512 + kglob;
      bool m;
      if (flagv == 0) m = (mask_i[midx] != 0);
      else if (flagv == 1) m = (mask_b[midx] != 0);
      else m = (mask_f[midx] != 0.f);
      s[q][kg] = m ? -1e9f : a;
    }
  }

  // ---- softmax ----
#pragma unroll
  for (int q = 0; q < TQ; q++) {
    float mx = s[q][0];
#pragma unroll
    for (int kg = 1; kg < 8; kg++) mx = fmaxf(mx, s[q][kg]);
#pragma unroll
    for (int off = 32; off > 0; off >>= 1) mx = fmaxf(mx, __shfl_xor(mx, off));
    float sum = 0.f;
#pragma unroll
    for (int kg = 0; kg < 8; kg++) {
      float e = __expf(s[q][kg] - mx);
      s[q][kg] = e;
      sum += e;
    }
#pragma unroll
    for (int off = 32; off > 0; off >>= 1) sum += __shfl_xor(sum, off);
    float inv = 1.f / sum;
#pragma unroll
    for (int kg = 0; kg < 8; kg++) s[q][kg] *= inv;
  }

  // ---- phase 2: per k-tile: gate + AV (kg fully unrolled) ----
  const int dv = lane & 31;
  const int qb = lane >> 5;
  float avacc[4] = {0.f, 0.f, 0.f, 0.f};

#pragma unroll
  for (int kg = 0; kg < 8; kg++) {
    __syncthreads();
#pragma unroll
    for (int q = 0; q < TQ; q++) P[h][q][lane] = s[q][kg];
    {
      int gq = tid >> 6, gk = tid & 63;
      M1[gq][gk] = matrix[((b << 9) + q0 + gq) * 512 + kg * 64 + gk];
    }
#pragma unroll
    for (int it = 0; it < 4; it++) {
      int idx = tid + it * 512;
      int kk = idx >> 5, c8 = (idx & 31) * 8;
      *(uint4*)&Vs[kk][c8] =
          *(const uint4*)&Vb[((b << 9) + kg * 64 + kk) * 256 + c8];
    }
    __syncthreads();

    // gate
    {
      int gq = tid >> 6, gk = tid & 63;
      float v[9];
      v[0] = M1[gq][gk];
#pragma unroll
      for (int hh = 0; hh < NH; hh++) v[1 + hh] = P[hh][gq][gk];
      float mu = 0.f;
#pragma unroll
      for (int i = 0; i < 9; i++) mu += v[i];
      mu *= (1.f / 9.f);
      float var = 0.f;
#pragma unroll
      for (int i = 0; i < 9; i++) {
        float d = v[i] - mu;
        var += d * d;
      }
      var *= (1.f / 9.f);
      float inv = rsqrtf(var + 1e-5f);
      float y[9];
#pragma unroll
      for (int i = 0; i < 9; i++)
        y[i] = fup[i] * (v[i] - mu) * inv + fup[9 + i];
      float o = fup[84];
#pragma unroll
      for (int j = 0; j < 6; j++) {
        float z = fup[72 + j];
#pragma unroll
        for (int i = 0; i < 9; i++) z += y[i] * fup[18 + i * 6 + j];
        z = fmaxf(z, 0.f);
        o += z * fup[78 + j];
      }
      float gv = 1.f / (1.f + __expf(-o));
      gws[((b << 9) + q0 + gq) * 512 + kg * 64 + gk] = __float2bfloat16(gv);
    }

    // AV from LDS (unroll 4: lets compiler merge P reads into ds_read_b64)
#pragma unroll 4
    for (int kk = 0; kk < 64; kk++) {
      float vv = __bfloat162float(Vs[kk][h * 32 + dv]);
#pragma unroll
      for (int j = 0; j < 4; j++) avacc[j] += P[h][qb + 2 * j][kk] * vv;
    }
  }

#pragma unroll
  for (int j = 0; j < 4; j++)
    ctx[((b << 9) + q0 + qb + 2 * j) * 256 + h * 32 + dv] = avacc[j];
}

// ---------------------------------------------------------------------------
// K3: mout[b,j,i] = matrix[b,j,i] * g[b,i,j]. 64x64 tiles, LDS transpose.
__global__ __launch_bounds__(256) void mout_kernel(
    const float* __restrict__ matrix, const __hip_bfloat16* __restrict__ g,
    float* __restrict__ mout) {
  __shared__ float Gs[64][65];
  const int tid = threadIdx.x;
  const int b = blockIdx.x >> 6;
  const int j0 = ((blockIdx.x >> 3) & 7) * 64;
  const int i0 = (blockIdx.x & 7) * 64;

  {
    int r = tid >> 2, c0 = (tid & 3) * 16;
    const __hip_bfloat16* gp = g + (((b << 9) + i0 + r) << 9) + j0 + c0;
    ushort us[16];
    *(uint4*)(us) = *(const uint4*)(gp);
    *(uint4*)(us + 8) = *(const uint4*)(gp + 8);
#pragma unroll
    for (int k = 0; k < 16; k++) {
      __hip_bfloat16 hv = *(__hip_bfloat16*)&us[k];
      Gs[r][c0 + k] = __bfloat162float(hv);
    }
  }
  __syncthreads();

  {
    int jj = tid >> 2, ic = (tid & 3) * 16;
    const float* mp = matrix + (((b << 9) + j0 + jj) << 9) + i0 + ic;
    float* op = mout + (((b << 9) + j0 + jj) << 9) + i0 + ic;
#pragma unroll
    for (int v4 = 0; v4 < 4; v4++) {
      float4 m = *(const float4*)(mp + v4 * 4);
      float4 o;
      o.x = m.x * Gs[ic + v4 * 4 + 0][jj];
      o.y = m.y * Gs[ic + v4 * 4 + 1][jj];
      o.z = m.z * Gs[ic + v4 * 4 + 2][jj];
      o.w = m.w * Gs[ic + v4 * 4 + 3][jj];
      *(float4*)(op + v4 * 4) = o;
    }
  }
}

// ---------------------------------------------------------------------------
// K4: context2[b,s,dv] = sum_k matrix[b,s,k] * Vp2[b,k,dv]. LDS-tiled:
// 16 s-rows per block, k in 4 chunks of 128. Grid 512.
__global__ __launch_bounds__(256) void ctx2_kernel(
    const float* __restrict__ matrix, const float* __restrict__ Vp2,
    float* __restrict__ ctx2) {
  __shared__ float Ms[16][128];
  __shared__ float Vs2[128][32];
  const int t = threadIdx.x;
  const int b = blockIdx.x >> 5;
  const int s0 = (blockIdx.x & 31) * 16;
  const int dv = t & 31, rg = t >> 5;  // rg 0..7
  float acc0 = 0.f, acc1 = 0.f;
  for (int kc = 0; kc < 4; kc++) {
    __syncthreads();
#pragma unroll
    for (int it = 0; it < 8; it++) {
      int idx = t + it * 256;
      int r = idx >> 7, cc = idx & 127;
      Ms[r][cc] = matrix[((b << 9) + s0 + r) * 512 + kc * 128 + cc];
    }
#pragma unroll
    for (int it = 0; it < 4; it++) {
      int idx = t + it * 256;
      int k = idx >> 3, c4 = (idx & 7) * 4;
      *(float4*)&Vs2[k][c4] =
          *(const float4*)&Vp2[((b << 9) + kc * 128 + k) * 32 + c4];
    }
    __syncthreads();
    for (int k = 0; k < 128; k++) {
      float v = Vs2[k][dv];
      acc0 += Ms[rg][k] * v;
      acc1 += Ms[rg + 8][k] * v;
    }
  }
  ctx2[((b << 9) + s0 + rg) * 32 + dv] = acc0;
  ctx2[((b << 9) + s0 + rg + 8) * 32 + dv] = acc1;
}

// ---------------------------------------------------------------------------
// K5: output = LN( [ctx | ctx2] @ W_fc ). 16 rows/block, grid 512.
__global__ __launch_bounds__(512) void final_kernel(
    const float* __restrict__ ctx, const float* __restrict__ ctx2,
    const float* __restrict__ Wfc, const float* __restrict__ lng,
    const float* __restrict__ lnb, float* __restrict__ out) {
  __shared__ float xs[16][289];
  __shared__ float red[16][4][2];
  const int tid = threadIdx.x;
  const int c = tid & 255;
  const int hf = tid >> 8;
  const int rbase = hf * 8;
  const int lane = tid & 63, wid = (tid >> 6) & 3;
  const int r0 = blockIdx.x * 16;

  for (int e = tid; e < 16 * 288; e += 512) {
    int r = e / 288, i = e - r * 288;
    xs[r][i] = (i < 256) ? ctx[(r0 + r) * 256 + i]
                         : ctx2[(r0 + r) * 32 + (i - 256)];
  }
  __syncthreads();

  float acc[8];
#pragma unroll
  for (int r = 0; r < 8; r++) acc[r] = 0.f;
  for (int i = 0; i < 288; i++) {
    float w = Wfc[i * 256 + c];
#pragma unroll
    for (int r = 0; r < 8; r++) acc[r] += xs[rbase + r][i] * w;
  }

#pragma unroll
  for (int r = 0; r < 8; r++) {
    float s1 = acc[r], s2 = acc[r] * acc[r];
#pragma unroll
    for (int off = 32; off > 0; off >>= 1) {
      s1 += __shfl_xor(s1, off);
      s2 += __shfl_xor(s2, off);
    }
    if (lane == 0) {
      red[rbase + r][wid][0] = s1;
      red[rbase + r][wid][1] = s2;
    }
  }
  __syncthreads();

  float gt = lng[c], bt = lnb[c];
#pragma unroll
  for (int r = 0; r < 8; r++) {
    int row = rbase + r;
    float s1 = red[row][0][0] + red[row][1][0] + red[row][2][0] + red[row][3][0];
    float s2 = red[row][0][1] + red[row][1][1] + red[row][2][1] + red[row][3][1];
    float mu = s1 * (1.f / 256.f);
    float var = s2 * (1.f / 256.f) - mu * mu;
    float inv = rsqrtf(var + 1e-5f);
    out[(r0 + row) * 256 + c] = gt * (acc[r] - mu) * inv + bt;
  }
}

// ---------------------------------------------------------------------------
extern "C" void kernel_launch(void* const* d_in, const int* in_sizes, int n_in,
                              void* d_out, int out_size, void* d_ws,
                              size_t ws_size, hipStream_t stream) {
  const float* inQ = (const float*)d_in[0];
  const float* inK = (const float*)d_in[1];
  const float* inV = (const float*)d_in[2];
  const void* mask = d_in[3];
  const float* matrix = (const float*)d_in[4];
  const float* Wq = (const float*)d_in[5];
  const float* Wk = (const float*)d_in[6];
  const float* Wv = (const float*)d_in[7];
  const float* Wv2 = (const float*)d_in[8];
  const float* Wfc = (const float*)d_in[9];
  const float* lng = (const float*)d_in[10];
  const float* lnb = (const float*)d_in[11];
  const float* fulng = (const float*)d_in[12];
  const float* fulnb = (const float*)d_in[13];
  const float* fuw1 = (const float*)d_in[14];
  const float* fub1 = (const float*)d_in[15];
  const float* fuw2 = (const float*)d_in[16];
  const float* fub2 = (const float*)d_in[17];

  float* ws = (float*)d_ws;
  float* Qp = ws + OFF_QP;
  float* Kt = ws + OFF_KT;
  __hip_bfloat16* Vb = (__hip_bfloat16*)(ws + OFF_VB);
  float* Vp2 = ws + OFF_VP2;
  float* ctx = ws + OFF_CTX;
  float* ctx2 = ws + OFF_CTX2;
  __hip_bfloat16* gws = (__hip_bfloat16*)(ws + OFF_G);
  unsigned int* flag = (unsigned int*)(ws + OFF_FLAG);

  float* out = (float*)d_out;
  float* mout = out + BB * SS * DM;

  hipMemsetAsync(flag, 0, 4, stream);
  mask_or_kernel<<<64, 256, 0, stream>>>((const unsigned int*)mask, flag);
  proj_kernel<<<BB * SS / 16, 512, 0, stream>>>(inQ, inK, inV, Wq, Wk, Wv,
                                                Wv2, Qp, Kt, Vb, Vp2);
  attn_kernel<<<BB * (SS / TQ), 512, 0, stream>>>(
      Qp, Kt, Vb, mask, matrix, fulng, fulnb, fuw1, fub1, fuw2, fub2, ctx,
      gws, flag);
  mout_kernel<<<BB * 64, 256, 0, stream>>>(matrix, gws, mout);
  ctx2_kernel<<<BB * (SS / 16), 256, 0, stream>>>(matrix, Vp2, ctx2);
  final_kernel<<<BB * SS / 16, 512, 0, stream>>>(ctx, ctx2, Wfc, lng, lnb,
                                                 out);
}

// Round 5
// 735.394 us; speedup vs baseline: 4.0613x; 4.0613x over previous
//
#include <hip/hip_runtime.h>
#include <hip/hip_bf16.h>

#define BB 16
#define SS 512
#define DM 256
#define NH 8
#define DKK 32
#define DVV 32

// workspace layout in float units
#define OFF_QP   0
#define OFF_KT   2097152
#define OFF_VB   4194304   // bf16 V [b,s,c]: 2097152 elems = 1048576 floats
#define OFF_VP2  5242880
#define OFF_CTX  5505024
#define OFF_CTX2 7602176
#define OFF_G    7864320   // bf16 g [b,q,k]: 4194304 elems = 2097152 floats
#define OFF_FLAG 9961472

#define SCALE 0.17677669529663687f

// ---------------------------------------------------------------------------
// K0: OR-reduce first 64K words of the mask into *acc (acc pre-zeroed).
__global__ void mask_or_kernel(const unsigned int* __restrict__ w,
                               unsigned int* __restrict__ acc) {
  __shared__ unsigned int sh[256];
  unsigned int a = 0;
  int base = blockIdx.x * 1024;
  for (int i = threadIdx.x; i < 1024; i += 256) a |= w[base + i];
  sh[threadIdx.x] = a;
  __syncthreads();
  for (int s = 128; s > 0; s >>= 1) {
    if (threadIdx.x < s) sh[threadIdx.x] |= sh[threadIdx.x + s];
    __syncthreads();
  }
  if (threadIdx.x == 0) atomicOr(acc, sh[0]);
}

// ---------------------------------------------------------------------------
// K1: projections. 512 threads: c = tid&255, row-half hf = tid>>8 (8 rows
// each), 16 rows per block -> grid 512 (2 blocks/CU).
__global__ __launch_bounds__(512) void proj_kernel(
    const float* __restrict__ inQ, const float* __restrict__ inK,
    const float* __restrict__ inV,
    const float* __restrict__ Wq, const float* __restrict__ Wk,
    const float* __restrict__ Wv, const float* __restrict__ Wv2,
    float* __restrict__ Qp, float* __restrict__ Kt,
    __hip_bfloat16* __restrict__ Vb, float* __restrict__ Vp2) {
  __shared__ float xs[16][257];
  const int tid = threadIdx.x;
  const int c = tid & 255;
  const int hf = tid >> 8;
  const int rbase = hf * 8;
  const int r0 = blockIdx.x * 16;
  float acc[8];

  // ---- Q ----
  for (int e = tid; e < 16 * DM; e += 512) {
    int r = e >> 8, i = e & 255;
    xs[r][i] = inQ[(r0 + r) * DM + i];
  }
  __syncthreads();
#pragma unroll
  for (int r = 0; r < 8; r++) acc[r] = 0.f;
  for (int i = 0; i < DM; i++) {
    float w = Wq[i * 256 + c];
#pragma unroll
    for (int r = 0; r < 8; r++) acc[r] += xs[rbase + r][i] * w;
  }
#pragma unroll
  for (int r = 0; r < 8; r++) Qp[(r0 + rbase + r) * 256 + c] = acc[r];
  __syncthreads();

  // ---- K (store transposed per head: Kt[(b*256+c)*512 + s]) ----
  for (int e = tid; e < 16 * DM; e += 512) {
    int r = e >> 8, i = e & 255;
    xs[r][i] = inK[(r0 + r) * DM + i];
  }
  __syncthreads();
#pragma unroll
  for (int r = 0; r < 8; r++) acc[r] = 0.f;
  for (int i = 0; i < DM; i++) {
    float w = Wk[i * 256 + c];
#pragma unroll
    for (int r = 0; r < 8; r++) acc[r] += xs[rbase + r][i] * w;
  }
#pragma unroll
  for (int r = 0; r < 8; r++) {
    int rg = r0 + rbase + r;
    int b = rg >> 9, sidx = rg & 511;
    Kt[(b * 256 + c) * 512 + sidx] = acc[r];
  }
  __syncthreads();

  // ---- V (bf16 row-major out) ----
  for (int e = tid; e < 16 * DM; e += 512) {
    int r = e >> 8, i = e & 255;
    xs[r][i] = inV[(r0 + r) * DM + i];
  }
  __syncthreads();
#pragma unroll
  for (int r = 0; r < 8; r++) acc[r] = 0.f;
  for (int i = 0; i < DM; i++) {
    float w = Wv[i * 256 + c];
#pragma unroll
    for (int r = 0; r < 8; r++) acc[r] += xs[rbase + r][i] * w;
  }
#pragma unroll
  for (int r = 0; r < 8; r++)
    Vb[(r0 + rbase + r) * 256 + c] = __float2bfloat16(acc[r]);

  // ---- V2 (reuse V rows in LDS): one (row, col) per thread ----
  {
    int c2 = tid & 31, rr = tid >> 5;  // rr 0..15
    float a = 0.f;
    for (int i = 0; i < DM; i++) a += xs[rr][i] * Wv2[i * 32 + c2];
    Vp2[(r0 + rr) * 32 + c2] = a;
  }
}

// ---------------------------------------------------------------------------
// K2: fused scores + softmax + gate + AV. 512 threads (8 waves = 8 heads),
// q-tile of 4, grid 2048.
// DESIGN RULE (rounds 1-4 lesson): per-lane register state must be SMALL and
// STATICALLY indexed. All score/prob state lives in LDS (Sb, bf16), where
// dynamic indexing is legal. Rolled kg loops are pinned with unroll 1 so the
// scheduler can't hoist 8 batches of kc[32] loads (round-4 spill explosion).
__global__ __launch_bounds__(512) void attn_kernel(
    const float* __restrict__ Qp, const float* __restrict__ Kt,
    const __hip_bfloat16* __restrict__ Vb, const void* __restrict__ mask,
    const float* __restrict__ matrix,
    const float* __restrict__ fulng, const float* __restrict__ fulnb,
    const float* __restrict__ fuw1, const float* __restrict__ fub1,
    const float* __restrict__ fuw2, const float* __restrict__ fub2,
    float* __restrict__ ctx, __hip_bfloat16* __restrict__ gws,
    const unsigned int* __restrict__ orv) {
  __shared__ __hip_bfloat16 Sb[NH][4][512];  // 32 KB scores->probs
  __shared__ float Qs[4][DM];                // 4 KB
  __shared__ __hip_bfloat16 Vs[64][256];     // 32 KB V tile
  __shared__ float fup[85];

  const int tid = threadIdx.x;
  const int lane = tid & 63;
  const int h = tid >> 6;
  // XCD swizzle: XCD = blockIdx%8 -> 2 batches per XCD; consecutive blocks
  // on one XCD sweep q-tiles of the same b (Kt/Vb stay hot in that L2).
  const int b = ((blockIdx.x & 7) << 1) | (blockIdx.x >> 10);
  const int q0 = ((blockIdx.x >> 3) & 127) * 4;

  for (int e = tid; e < 4 * DM; e += 512) {
    int q = e >> 8, i = e & 255;
    Qs[q][i] = Qp[((b << 9) + q0 + q) * 256 + i];
  }
  if (tid < 9) fup[tid] = fulng[tid];
  else if (tid < 18) fup[tid] = fulnb[tid - 9];
  else if (tid < 72) fup[tid] = fuw1[tid - 18];
  else if (tid < 78) fup[tid] = fub1[tid - 72];
  else if (tid < 84) fup[tid] = fuw2[tid - 78];
  else if (tid == 84) fup[tid] = fub2[0];
  const unsigned int rawor = *orv;
  const int flagv = (rawor <= 1u) ? 0 : ((rawor == 0x3F800000u) ? 2 : 1);
  __syncthreads();

  const int* mask_i = (const int*)mask;
  const unsigned char* mask_b = (const unsigned char*)mask;
  const float* mask_f = (const float*)mask;

  // ---- phase 1: scores + mask -> Sb (bf16) ----
#pragma unroll 1
  for (int kg = 0; kg < 8; kg++) {
    int kglob = kg * 64 + lane;
    float kc[DKK];
#pragma unroll
    for (int d = 0; d < DKK; d++)
      kc[d] = Kt[(b * 256 + h * 32 + d) * 512 + kglob];
#pragma unroll
    for (int q = 0; q < 4; q++) {
      float a = 0.f;
#pragma unroll
      for (int d = 0; d < DKK; d++) a += Qs[q][h * 32 + d] * kc[d];
      a *= SCALE;
      int midx = ((b * 8 + h) * 512 + q0 + q) * 512 + kglob;
      bool m;
      if (flagv == 0) m = (mask_i[midx] != 0);
      else if (flagv == 1) m = (mask_b[midx] != 0);
      else m = (mask_f[midx] != 0.f);
      Sb[h][q][kglob] = __float2bfloat16(m ? -1e9f : a);
    }
  }
  // wave h wrote Sb[h] itself -> no barrier needed before its own softmax.

  // ---- softmax (per wave, 4 rows) ----
#pragma unroll
  for (int q = 0; q < 4; q++) {
    float v[8];
#pragma unroll
    for (int j = 0; j < 8; j++)
      v[j] = __bfloat162float(Sb[h][q][j * 64 + lane]);
    float mx = v[0];
#pragma unroll
    for (int j = 1; j < 8; j++) mx = fmaxf(mx, v[j]);
#pragma unroll
    for (int off = 32; off > 0; off >>= 1) mx = fmaxf(mx, __shfl_xor(mx, off));
    float sum = 0.f;
#pragma unroll
    for (int j = 0; j < 8; j++) {
      float e = __expf(v[j] - mx);
      v[j] = e;
      sum += e;
    }
#pragma unroll
    for (int off = 32; off > 0; off >>= 1) sum += __shfl_xor(sum, off);
    float inv = 1.f / sum;
#pragma unroll
    for (int j = 0; j < 8; j++)
      Sb[h][q][j * 64 + lane] = __float2bfloat16(v[j] * inv);
  }
  __syncthreads();  // all heads' probs visible to all threads

  // ---- gate: thread -> (gq, 4 consecutive k) ----
  {
    const int gq = tid >> 7;          // 0..3
    const int k0 = (tid & 127) * 4;   // 0..508
    float4 mrow = *(const float4*)&matrix[((b << 9) + q0 + gq) * 512 + k0];
    float p[NH][4];
#pragma unroll
    for (int hh = 0; hh < NH; hh++) {
      ushort4 sv = *(const ushort4*)&Sb[hh][gq][k0];
      p[hh][0] = __bfloat162float(*(__hip_bfloat16*)&sv.x);
      p[hh][1] = __bfloat162float(*(__hip_bfloat16*)&sv.y);
      p[hh][2] = __bfloat162float(*(__hip_bfloat16*)&sv.z);
      p[hh][3] = __bfloat162float(*(__hip_bfloat16*)&sv.w);
    }
    const float mcomp[4] = {mrow.x, mrow.y, mrow.z, mrow.w};
    __hip_bfloat16 gout[4];
#pragma unroll
    for (int i = 0; i < 4; i++) {
      float v[9];
      v[0] = mcomp[i];
#pragma unroll
      for (int hh = 0; hh < NH; hh++) v[1 + hh] = p[hh][i];
      float mu = 0.f;
#pragma unroll
      for (int t = 0; t < 9; t++) mu += v[t];
      mu *= (1.f / 9.f);
      float var = 0.f;
#pragma unroll
      for (int t = 0; t < 9; t++) {
        float d = v[t] - mu;
        var += d * d;
      }
      var *= (1.f / 9.f);
      float inv = rsqrtf(var + 1e-5f);
      float y[9];
#pragma unroll
      for (int t = 0; t < 9; t++)
        y[t] = fup[t] * (v[t] - mu) * inv + fup[9 + t];
      float o = fup[84];
#pragma unroll
      for (int j = 0; j < 6; j++) {
        float z = fup[72 + j];
#pragma unroll
        for (int t = 0; t < 9; t++) z += y[t] * fup[18 + t * 6 + j];
        z = fmaxf(z, 0.f);
        o += z * fup[78 + j];
      }
      gout[i] = __float2bfloat16(1.f / (1.f + __expf(-o)));
    }
    *(ushort4*)&gws[((b << 9) + q0 + gq) * 512 + k0] = *(ushort4*)gout;
  }

  // ---- AV: per k-tile, V staged in LDS; probs from Sb ----
  const int dv = lane & 31;
  const int qb = lane >> 5;  // rows qb and qb+2
  float avacc0 = 0.f, avacc1 = 0.f;

#pragma unroll 1
  for (int kg = 0; kg < 8; kg++) {
    __syncthreads();
#pragma unroll
    for (int it = 0; it < 4; it++) {
      int idx = tid + it * 512;
      int kk = idx >> 5, c8 = (idx & 31) * 8;
      *(uint4*)&Vs[kk][c8] =
          *(const uint4*)&Vb[((b << 9) + kg * 64 + kk) * 256 + c8];
    }
    __syncthreads();
#pragma unroll 4
    for (int kk = 0; kk < 64; kk++) {
      float vv = __bfloat162float(Vs[kk][h * 32 + dv]);
      avacc0 += __bfloat162float(Sb[h][qb][kg * 64 + kk]) * vv;
      avacc1 += __bfloat162float(Sb[h][qb + 2][kg * 64 + kk]) * vv;
    }
  }

  ctx[((b << 9) + q0 + qb) * 256 + h * 32 + dv] = avacc0;
  ctx[((b << 9) + q0 + qb + 2) * 256 + h * 32 + dv] = avacc1;
}

// ---------------------------------------------------------------------------
// K3: mout[b,j,i] = matrix[b,j,i] * g[b,i,j]. 64x64 tiles, LDS transpose.
__global__ __launch_bounds__(256) void mout_kernel(
    const float* __restrict__ matrix, const __hip_bfloat16* __restrict__ g,
    float* __restrict__ mout) {
  __shared__ float Gs[64][65];
  const int tid = threadIdx.x;
  const int b = blockIdx.x >> 6;
  const int j0 = ((blockIdx.x >> 3) & 7) * 64;
  const int i0 = (blockIdx.x & 7) * 64;

  {
    int r = tid >> 2, c0 = (tid & 3) * 16;
    const __hip_bfloat16* gp = g + (((b << 9) + i0 + r) << 9) + j0 + c0;
    ushort us[16];
    *(uint4*)(us) = *(const uint4*)(gp);
    *(uint4*)(us + 8) = *(const uint4*)(gp + 8);
#pragma unroll
    for (int k = 0; k < 16; k++) {
      __hip_bfloat16 hv = *(__hip_bfloat16*)&us[k];
      Gs[r][c0 + k] = __bfloat162float(hv);
    }
  }
  __syncthreads();

  {
    int jj = tid >> 2, ic = (tid & 3) * 16;
    const float* mp = matrix + (((b << 9) + j0 + jj) << 9) + i0 + ic;
    float* op = mout + (((b << 9) + j0 + jj) << 9) + i0 + ic;
#pragma unroll
    for (int v4 = 0; v4 < 4; v4++) {
      float4 m = *(const float4*)(mp + v4 * 4);
      float4 o;
      o.x = m.x * Gs[ic + v4 * 4 + 0][jj];
      o.y = m.y * Gs[ic + v4 * 4 + 1][jj];
      o.z = m.z * Gs[ic + v4 * 4 + 2][jj];
      o.w = m.w * Gs[ic + v4 * 4 + 3][jj];
      *(float4*)(op + v4 * 4) = o;
    }
  }
}

// ---------------------------------------------------------------------------
// K4: context2[b,s,dv] = sum_k matrix[b,s,k] * Vp2[b,k,dv]. LDS-tiled:
// 16 s-rows per block, k in 4 chunks of 128. Grid 512.
__global__ __launch_bounds__(256) void ctx2_kernel(
    const float* __restrict__ matrix, const float* __restrict__ Vp2,
    float* __restrict__ ctx2) {
  __shared__ float Ms[16][128];
  __shared__ float Vs2[128][32];
  const int t = threadIdx.x;
  const int b = blockIdx.x >> 5;
  const int s0 = (blockIdx.x & 31) * 16;
  const int dv = t & 31, rg = t >> 5;  // rg 0..7
  float acc0 = 0.f, acc1 = 0.f;
  for (int kc = 0; kc < 4; kc++) {
    __syncthreads();
#pragma unroll
    for (int it = 0; it < 8; it++) {
      int idx = t + it * 256;
      int r = idx >> 7, cc = idx & 127;
      Ms[r][cc] = matrix[((b << 9) + s0 + r) * 512 + kc * 128 + cc];
    }
#pragma unroll
    for (int it = 0; it < 4; it++) {
      int idx = t + it * 256;
      int k = idx >> 3, c4 = (idx & 7) * 4;
      *(float4*)&Vs2[k][c4] =
          *(const float4*)&Vp2[((b << 9) + kc * 128 + k) * 32 + c4];
    }
    __syncthreads();
    for (int k = 0; k < 128; k++) {
      float v = Vs2[k][dv];
      acc0 += Ms[rg][k] * v;
      acc1 += Ms[rg + 8][k] * v;
    }
  }
  ctx2[((b << 9) + s0 + rg) * 32 + dv] = acc0;
  ctx2[((b << 9) + s0 + rg + 8) * 32 + dv] = acc1;
}

// ---------------------------------------------------------------------------
// K5: output = LN( [ctx | ctx2] @ W_fc ). 16 rows/block, grid 512.
__global__ __launch_bounds__(512) void final_kernel(
    const float* __restrict__ ctx, const float* __restrict__ ctx2,
    const float* __restrict__ Wfc, const float* __restrict__ lng,
    const float* __restrict__ lnb, float* __restrict__ out) {
  __shared__ float xs[16][289];
  __shared__ float red[16][4][2];
  const int tid = threadIdx.x;
  const int c = tid & 255;
  const int hf = tid >> 8;
  const int rbase = hf * 8;
  const int lane = tid & 63, wid = (tid >> 6) & 3;
  const int r0 = blockIdx.x * 16;

  for (int e = tid; e < 16 * 288; e += 512) {
    int r = e / 288, i = e - r * 288;
    xs[r][i] = (i < 256) ? ctx[(r0 + r) * 256 + i]
                         : ctx2[(r0 + r) * 32 + (i - 256)];
  }
  __syncthreads();

  float acc[8];
#pragma unroll
  for (int r = 0; r < 8; r++) acc[r] = 0.f;
  for (int i = 0; i < 288; i++) {
    float w = Wfc[i * 256 + c];
#pragma unroll
    for (int r = 0; r < 8; r++) acc[r] += xs[rbase + r][i] * w;
  }

#pragma unroll
  for (int r = 0; r < 8; r++) {
    float s1 = acc[r], s2 = acc[r] * acc[r];
#pragma unroll
    for (int off = 32; off > 0; off >>= 1) {
      s1 += __shfl_xor(s1, off);
      s2 += __shfl_xor(s2, off);
    }
    if (lane == 0) {
      red[rbase + r][wid][0] = s1;
      red[rbase + r][wid][1] = s2;
    }
  }
  __syncthreads();

  float gt = lng[c], bt = lnb[c];
#pragma unroll
  for (int r = 0; r < 8; r++) {
    int row = rbase + r;
    float s1 = red[row][0][0] + red[row][1][0] + red[row][2][0] + red[row][3][0];
    float s2 = red[row][0][1] + red[row][1][1] + red[row][2][1] + red[row][3][1];
    float mu = s1 * (1.f / 256.f);
    float var = s2 * (1.f / 256.f) - mu * mu;
    float inv = rsqrtf(var + 1e-5f);
    out[(r0 + row) * 256 + c] = gt * (acc[r] - mu) * inv + bt;
  }
}

// ---------------------------------------------------------------------------
extern "C" void kernel_launch(void* const* d_in, const int* in_sizes, int n_in,
                              void* d_out, int out_size, void* d_ws,
                              size_t ws_size, hipStream_t stream) {
  const float* inQ = (const float*)d_in[0];
  const float* inK = (const float*)d_in[1];
  const float* inV = (const float*)d_in[2];
  const void* mask = d_in[3];
  const float* matrix = (const float*)d_in[4];
  const float* Wq = (const float*)d_in[5];
  const float* Wk = (const float*)d_in[6];
  const float* Wv = (const float*)d_in[7];
  const float* Wv2 = (const float*)d_in[8];
  const float* Wfc = (const float*)d_in[9];
  const float* lng = (const float*)d_in[10];
  const float* lnb = (const float*)d_in[11];
  const float* fulng = (const float*)d_in[12];
  const float* fulnb = (const float*)d_in[13];
  const float* fuw1 = (const float*)d_in[14];
  const float* fub1 = (const float*)d_in[15];
  const float* fuw2 = (const float*)d_in[16];
  const float* fub2 = (const float*)d_in[17];

  float* ws = (float*)d_ws;
  float* Qp = ws + OFF_QP;
  float* Kt = ws + OFF_KT;
  __hip_bfloat16* Vb = (__hip_bfloat16*)(ws + OFF_VB);
  float* Vp2 = ws + OFF_VP2;
  float* ctx = ws + OFF_CTX;
  float* ctx2 = ws + OFF_CTX2;
  __hip_bfloat16* gws = (__hip_bfloat16*)(ws + OFF_G);
  unsigned int* flag = (unsigned int*)(ws + OFF_FLAG);

  float* out = (float*)d_out;
  float* mout = out + BB * SS * DM;

  hipMemsetAsync(flag, 0, 4, stream);
  mask_or_kernel<<<64, 256, 0, stream>>>((const unsigned int*)mask, flag);
  proj_kernel<<<BB * SS / 16, 512, 0, stream>>>(inQ, inK, inV, Wq, Wk, Wv,
                                                Wv2, Qp, Kt, Vb, Vp2);
  attn_kernel<<<BB * (SS / 4), 512, 0, stream>>>(
      Qp, Kt, Vb, mask, matrix, fulng, fulnb, fuw1, fub1, fuw2, fub2, ctx,
      gws, flag);
  mout_kernel<<<BB * 64, 256, 0, stream>>>(matrix, gws, mout);
  ctx2_kernel<<<BB * (SS / 16), 256, 0, stream>>>(matrix, Vp2, ctx2);
  final_kernel<<<BB * SS / 16, 512, 0, stream>>>(ctx, ctx2, Wfc, lng, lnb,
                                                 out);
}

// Round 6
// 583.969 us; speedup vs baseline: 5.1144x; 1.2593x over previous
//
#include <hip/hip_runtime.h>
#include <hip/hip_bf16.h>

#define BB 16
#define SS 512
#define DM 256
#define NH 8
#define DKK 32
#define DVV 32

// workspace layout in float units
#define OFF_QB   0         // bf16 Q [b,s,c]   2097152 elem
#define OFF_KB   1048576   // bf16 K [b,s,c]   2097152 elem
#define OFF_VT   2097152   // bf16 V^T [b,c,s] 2097152 elem
#define OFF_VP2  3145728   // f32 [b,s,32]
#define OFF_CTX  3407872   // f32 [b,s,256]
#define OFF_CTX2 5505024   // f32 [b,s,32]
#define OFF_G    5767168   // bf16 g [b,q,k]   4194304 elem
#define OFF_FLAG 7864320

#define SCALE 0.17677669529663687f

typedef __attribute__((ext_vector_type(8))) short bfrag8;  // 8 bf16 (4 VGPR)
typedef __attribute__((ext_vector_type(4))) float facc4;   // MFMA accumulator

// ---------------------------------------------------------------------------
// K0: OR-reduce first 64K words of the mask into *acc (acc pre-zeroed).
__global__ void mask_or_kernel(const unsigned int* __restrict__ w,
                               unsigned int* __restrict__ acc) {
  __shared__ unsigned int sh[256];
  unsigned int a = 0;
  int base = blockIdx.x * 1024;
  for (int i = threadIdx.x; i < 1024; i += 256) a |= w[base + i];
  sh[threadIdx.x] = a;
  __syncthreads();
  for (int s = 128; s > 0; s >>= 1) {
    if (threadIdx.x < s) sh[threadIdx.x] |= sh[threadIdx.x + s];
    __syncthreads();
  }
  if (threadIdx.x == 0) atomicOr(acc, sh[0]);
}

// ---------------------------------------------------------------------------
// K1: projections. 512 threads: c = tid&255, row-half hf = tid>>8 (8 rows
// each), 16 rows/block, grid 512. Outputs: Qb,Kb bf16 row-major (MFMA A/B
// frags read 16B contiguous), Vt bf16 transposed [b,c,s], Vp2 f32.
__global__ __launch_bounds__(512) void proj_kernel(
    const float* __restrict__ inQ, const float* __restrict__ inK,
    const float* __restrict__ inV,
    const float* __restrict__ Wq, const float* __restrict__ Wk,
    const float* __restrict__ Wv, const float* __restrict__ Wv2,
    __hip_bfloat16* __restrict__ Qb, __hip_bfloat16* __restrict__ Kb,
    __hip_bfloat16* __restrict__ Vt, float* __restrict__ Vp2) {
  __shared__ __align__(16) float xs[16][260];  // stride 260: 16B-aligned rows
  const int tid = threadIdx.x;
  const int c = tid & 255;
  const int hf = tid >> 8;
  const int rbase = hf * 8;
  const int r0 = blockIdx.x * 16;
  float acc[8];

  // ---- Q ----
  for (int e = tid; e < 16 * DM; e += 512) {
    int r = e >> 8, i = e & 255;
    xs[r][i] = inQ[(r0 + r) * DM + i];
  }
  __syncthreads();
#pragma unroll
  for (int r = 0; r < 8; r++) acc[r] = 0.f;
  for (int i = 0; i < DM; i += 4) {
    float w0 = Wq[i * 256 + c], w1 = Wq[(i + 1) * 256 + c];
    float w2 = Wq[(i + 2) * 256 + c], w3 = Wq[(i + 3) * 256 + c];
#pragma unroll
    for (int r = 0; r < 8; r++) {
      float4 xv = *(const float4*)&xs[rbase + r][i];
      acc[r] += xv.x * w0 + xv.y * w1 + xv.z * w2 + xv.w * w3;
    }
  }
#pragma unroll
  for (int r = 0; r < 8; r++)
    Qb[(r0 + rbase + r) * 256 + c] = __float2bfloat16(acc[r]);
  __syncthreads();

  // ---- K (row-major bf16) ----
  for (int e = tid; e < 16 * DM; e += 512) {
    int r = e >> 8, i = e & 255;
    xs[r][i] = inK[(r0 + r) * DM + i];
  }
  __syncthreads();
#pragma unroll
  for (int r = 0; r < 8; r++) acc[r] = 0.f;
  for (int i = 0; i < DM; i += 4) {
    float w0 = Wk[i * 256 + c], w1 = Wk[(i + 1) * 256 + c];
    float w2 = Wk[(i + 2) * 256 + c], w3 = Wk[(i + 3) * 256 + c];
#pragma unroll
    for (int r = 0; r < 8; r++) {
      float4 xv = *(const float4*)&xs[rbase + r][i];
      acc[r] += xv.x * w0 + xv.y * w1 + xv.z * w2 + xv.w * w3;
    }
  }
#pragma unroll
  for (int r = 0; r < 8; r++)
    Kb[(r0 + rbase + r) * 256 + c] = __float2bfloat16(acc[r]);
  __syncthreads();

  // ---- V (store transposed: Vt[(b*256+c)*512 + s]) ----
  for (int e = tid; e < 16 * DM; e += 512) {
    int r = e >> 8, i = e & 255;
    xs[r][i] = inV[(r0 + r) * DM + i];
  }
  __syncthreads();
#pragma unroll
  for (int r = 0; r < 8; r++) acc[r] = 0.f;
  for (int i = 0; i < DM; i += 4) {
    float w0 = Wv[i * 256 + c], w1 = Wv[(i + 1) * 256 + c];
    float w2 = Wv[(i + 2) * 256 + c], w3 = Wv[(i + 3) * 256 + c];
#pragma unroll
    for (int r = 0; r < 8; r++) {
      float4 xv = *(const float4*)&xs[rbase + r][i];
      acc[r] += xv.x * w0 + xv.y * w1 + xv.z * w2 + xv.w * w3;
    }
  }
#pragma unroll
  for (int r = 0; r < 8; r++) {
    int rg = r0 + rbase + r;
    int b = rg >> 9, sidx = rg & 511;
    Vt[((b * 256 + c) << 9) + sidx] = __float2bfloat16(acc[r]);
  }

  // ---- V2 (reuse V rows in LDS): one (row, col) per thread ----
  {
    int c2 = tid & 31, rr = tid >> 5;  // rr 0..15
    float a = 0.f;
    for (int i = 0; i < DM; i += 4) {
      float4 xv = *(const float4*)&xs[rr][i];
      a += xv.x * Wv2[i * 32 + c2] + xv.y * Wv2[(i + 1) * 32 + c2] +
           xv.z * Wv2[(i + 2) * 32 + c2] + xv.w * Wv2[(i + 3) * 32 + c2];
    }
    Vp2[(r0 + rr) * 32 + c2] = a;
  }
}

// ---------------------------------------------------------------------------
// K2: fused scores(MFMA) + softmax + gate + AV(MFMA). 512 thr (wave=head),
// q-tile 4, grid 2048. Scores/probs in LDS Sb (stride 520: bank-friendly,
// 16B-aligned frags). M=16 MFMA carries 4 real q rows (zero-padded lanes).
// Lessons: per-lane state small+static (r1-4); no min-wave bound (r2).
__global__ __launch_bounds__(512) void attn_kernel(
    const __hip_bfloat16* __restrict__ Qb, const __hip_bfloat16* __restrict__ Kb,
    const __hip_bfloat16* __restrict__ Vt, const void* __restrict__ mask,
    const float* __restrict__ matrix,
    const float* __restrict__ fulng, const float* __restrict__ fulnb,
    const float* __restrict__ fuw1, const float* __restrict__ fub1,
    const float* __restrict__ fuw2, const float* __restrict__ fub2,
    float* __restrict__ ctx, __hip_bfloat16* __restrict__ gws,
    const unsigned int* __restrict__ orv) {
  __shared__ __align__(16) __hip_bfloat16 Sb[NH][4][520];  // 33.3 KB
  __shared__ float fup[85];

  const int tid = threadIdx.x;
  const int lane = tid & 63;
  const int h = tid >> 6;
  const int cl = lane & 15;    // MFMA col lane
  const int quad = lane >> 4;  // MFMA k-chunk
  // XCD swizzle: 2 batches per XCD.
  const int b = ((blockIdx.x & 7) << 1) | (blockIdx.x >> 10);
  const int q0 = ((blockIdx.x >> 3) & 127) * 4;

  if (tid < 9) fup[tid] = fulng[tid];
  else if (tid < 18) fup[tid] = fulnb[tid - 9];
  else if (tid < 72) fup[tid] = fuw1[tid - 18];
  else if (tid < 78) fup[tid] = fub1[tid - 72];
  else if (tid < 84) fup[tid] = fuw2[tid - 78];
  else if (tid == 84) fup[tid] = fub2[0];
  const unsigned int rawor = *orv;
  const int flagv = (rawor <= 1u) ? 0 : ((rawor == 0x3F800000u) ? 2 : 1);

  const int* mask_i = (const int*)mask;
  const unsigned char* mask_b = (const unsigned char*)mask;
  const float* mask_f = (const float*)mask;

  // ---- phase 1: raw scores via MFMA. A = Q rows (m<4 real), B = K^T. ----
  bfrag8 aQ = {0, 0, 0, 0, 0, 0, 0, 0};
  if (cl < 4)
    aQ = *(const bfrag8*)&Qb[(((b << 9) + q0 + cl) << 8) + h * 32 + quad * 8];
#pragma unroll 4
  for (int nt = 0; nt < 32; nt++) {
    bfrag8 bK =
        *(const bfrag8*)&Kb[(((b << 9) + nt * 16 + cl) << 8) + h * 32 + quad * 8];
    facc4 cacc = {0.f, 0.f, 0.f, 0.f};
    cacc = __builtin_amdgcn_mfma_f32_16x16x32_bf16(aQ, bK, cacc, 0, 0, 0);
    if (quad == 0) {  // C rows 0..3 = q rows (row = quad*4+reg)
#pragma unroll
      for (int reg = 0; reg < 4; reg++)
        Sb[h][reg][nt * 16 + cl] = __float2bfloat16(cacc[reg]);
    }
  }

  // ---- softmax (scale+mask applied here; coalesced mask loads) ----
#pragma unroll
  for (int q = 0; q < 4; q++) {
    float v[8];
#pragma unroll
    for (int j = 0; j < 8; j++) {
      float raw = __bfloat162float(Sb[h][q][j * 64 + lane]) * SCALE;
      int midx = ((b * 8 + h) * 512 + q0 + q) * 512 + j * 64 + lane;
      bool m;
      if (flagv == 0) m = (mask_i[midx] != 0);
      else if (flagv == 1) m = (mask_b[midx] != 0);
      else m = (mask_f[midx] != 0.f);
      v[j] = m ? -1e9f : raw;
    }
    float mx = v[0];
#pragma unroll
    for (int j = 1; j < 8; j++) mx = fmaxf(mx, v[j]);
#pragma unroll
    for (int off = 32; off > 0; off >>= 1) mx = fmaxf(mx, __shfl_xor(mx, off));
    float sum = 0.f;
#pragma unroll
    for (int j = 0; j < 8; j++) {
      float e = __expf(v[j] - mx);
      v[j] = e;
      sum += e;
    }
#pragma unroll
    for (int off = 32; off > 0; off >>= 1) sum += __shfl_xor(sum, off);
    float inv = 1.f / sum;
#pragma unroll
    for (int j = 0; j < 8; j++)
      Sb[h][q][j * 64 + lane] = __float2bfloat16(v[j] * inv);
  }
  __syncthreads();  // all heads' probs visible

  // ---- gate: thread -> (gq, 4 consecutive k) ----
  {
    const int gq = tid >> 7;
    const int k0 = (tid & 127) * 4;
    float4 mrow = *(const float4*)&matrix[((b << 9) + q0 + gq) * 512 + k0];
    float p[NH][4];
#pragma unroll
    for (int hh = 0; hh < NH; hh++) {
      ushort4 sv = *(const ushort4*)&Sb[hh][gq][k0];
      p[hh][0] = __bfloat162float(*(__hip_bfloat16*)&sv.x);
      p[hh][1] = __bfloat162float(*(__hip_bfloat16*)&sv.y);
      p[hh][2] = __bfloat162float(*(__hip_bfloat16*)&sv.z);
      p[hh][3] = __bfloat162float(*(__hip_bfloat16*)&sv.w);
    }
    const float mcomp[4] = {mrow.x, mrow.y, mrow.z, mrow.w};
    __hip_bfloat16 gout[4];
#pragma unroll
    for (int i = 0; i < 4; i++) {
      float v[9];
      v[0] = mcomp[i];
#pragma unroll
      for (int hh = 0; hh < NH; hh++) v[1 + hh] = p[hh][i];
      float mu = 0.f;
#pragma unroll
      for (int t = 0; t < 9; t++) mu += v[t];
      mu *= (1.f / 9.f);
      float var = 0.f;
#pragma unroll
      for (int t = 0; t < 9; t++) {
        float d = v[t] - mu;
        var += d * d;
      }
      var *= (1.f / 9.f);
      float inv = rsqrtf(var + 1e-5f);
      float y[9];
#pragma unroll
      for (int t = 0; t < 9; t++)
        y[t] = fup[t] * (v[t] - mu) * inv + fup[9 + t];
      float o = fup[84];
#pragma unroll
      for (int j = 0; j < 6; j++) {
        float z = fup[72 + j];
#pragma unroll
        for (int t = 0; t < 9; t++) z += y[t] * fup[18 + t * 6 + j];
        z = fmaxf(z, 0.f);
        o += z * fup[78 + j];
      }
      gout[i] = __float2bfloat16(1.f / (1.f + __expf(-o)));
    }
    *(ushort4*)&gws[((b << 9) + q0 + gq) * 512 + k0] = *(ushort4*)gout;
  }

  // ---- AV via MFMA: A = probs (Sb), B = V^T rows from global ----
  facc4 a0 = {0.f, 0.f, 0.f, 0.f}, a1 = {0.f, 0.f, 0.f, 0.f};
#pragma unroll 2
  for (int kb = 0; kb < 16; kb++) {
    bfrag8 aP = {0, 0, 0, 0, 0, 0, 0, 0};
    if (cl < 4) aP = *(const bfrag8*)&Sb[h][cl][kb * 32 + quad * 8];
    bfrag8 b0 =
        *(const bfrag8*)&Vt[(((b << 8) + h * 32 + cl) << 9) + kb * 32 + quad * 8];
    bfrag8 b1 = *(const bfrag8*)&Vt[(((b << 8) + h * 32 + 16 + cl) << 9) +
                                    kb * 32 + quad * 8];
    a0 = __builtin_amdgcn_mfma_f32_16x16x32_bf16(aP, b0, a0, 0, 0, 0);
    a1 = __builtin_amdgcn_mfma_f32_16x16x32_bf16(aP, b1, a1, 0, 0, 0);
  }
  if (quad == 0) {
#pragma unroll
    for (int reg = 0; reg < 4; reg++) {
      ctx[((b << 9) + q0 + reg) * 256 + h * 32 + cl] = a0[reg];
      ctx[((b << 9) + q0 + reg) * 256 + h * 32 + 16 + cl] = a1[reg];
    }
  }
}

// ---------------------------------------------------------------------------
// K3: mout[b,j,i] = matrix[b,j,i] * g[b,i,j]. 64x64 tiles, LDS transpose.
__global__ __launch_bounds__(256) void mout_kernel(
    const float* __restrict__ matrix, const __hip_bfloat16* __restrict__ g,
    float* __restrict__ mout) {
  __shared__ float Gs[64][65];
  const int tid = threadIdx.x;
  const int b = blockIdx.x >> 6;
  const int j0 = ((blockIdx.x >> 3) & 7) * 64;
  const int i0 = (blockIdx.x & 7) * 64;

  {
    int r = tid >> 2, c0 = (tid & 3) * 16;
    const __hip_bfloat16* gp = g + (((b << 9) + i0 + r) << 9) + j0 + c0;
    ushort us[16];
    *(uint4*)(us) = *(const uint4*)(gp);
    *(uint4*)(us + 8) = *(const uint4*)(gp + 8);
#pragma unroll
    for (int k = 0; k < 16; k++) {
      __hip_bfloat16 hv = *(__hip_bfloat16*)&us[k];
      Gs[r][c0 + k] = __bfloat162float(hv);
    }
  }
  __syncthreads();

  {
    int jj = tid >> 2, ic = (tid & 3) * 16;
    const float* mp = matrix + (((b << 9) + j0 + jj) << 9) + i0 + ic;
    float* op = mout + (((b << 9) + j0 + jj) << 9) + i0 + ic;
#pragma unroll
    for (int v4 = 0; v4 < 4; v4++) {
      float4 m = *(const float4*)(mp + v4 * 4);
      float4 o;
      o.x = m.x * Gs[ic + v4 * 4 + 0][jj];
      o.y = m.y * Gs[ic + v4 * 4 + 1][jj];
      o.z = m.z * Gs[ic + v4 * 4 + 2][jj];
      o.w = m.w * Gs[ic + v4 * 4 + 3][jj];
      *(float4*)(op + v4 * 4) = o;
    }
  }
}

// ---------------------------------------------------------------------------
// K4: context2[b,s,dv] = sum_k matrix[b,s,k] * Vp2[b,k,dv]. Vp2 staged
// TRANSPOSED in LDS so the inner loop reads b128 along k. Grid 512.
__global__ __launch_bounds__(256) void ctx2_kernel(
    const float* __restrict__ matrix, const float* __restrict__ Vp2,
    float* __restrict__ ctx2) {
  __shared__ __align__(16) float Ms[16][128];
  __shared__ __align__(16) float Vs2t[32][132];  // [dv][k], pad 132
  const int t = threadIdx.x;
  const int b = blockIdx.x >> 5;
  const int s0 = (blockIdx.x & 31) * 16;
  const int dv = t & 31, rg = t >> 5;  // rg 0..7
  float acc0 = 0.f, acc1 = 0.f;
  for (int kc = 0; kc < 4; kc++) {
    __syncthreads();
#pragma unroll
    for (int it = 0; it < 8; it++) {
      int idx = t + it * 256;
      int r = idx >> 7, cc = idx & 127;
      Ms[r][cc] = matrix[((b << 9) + s0 + r) * 512 + kc * 128 + cc];
    }
#pragma unroll
    for (int it = 0; it < 16; it += 1) {
      int e = t + it * 256;  // 4096 elems: k = e>>5, dv2 = e&31
      int k = e >> 5, dv2 = e & 31;
      Vs2t[dv2][k] = Vp2[((b << 9) + kc * 128 + k) * 32 + dv2];
    }
    __syncthreads();
    for (int k = 0; k < 128; k += 4) {
      float4 vv = *(const float4*)&Vs2t[dv][k];
      float4 m0 = *(const float4*)&Ms[rg][k];
      float4 m1 = *(const float4*)&Ms[rg + 8][k];
      acc0 += m0.x * vv.x + m0.y * vv.y + m0.z * vv.z + m0.w * vv.w;
      acc1 += m1.x * vv.x + m1.y * vv.y + m1.z * vv.z + m1.w * vv.w;
    }
  }
  ctx2[((b << 9) + s0 + rg) * 32 + dv] = acc0;
  ctx2[((b << 9) + s0 + rg + 8) * 32 + dv] = acc1;
}

// ---------------------------------------------------------------------------
// K5: output = LN( [ctx | ctx2] @ W_fc ). 16 rows/block, grid 512.
__global__ __launch_bounds__(512) void final_kernel(
    const float* __restrict__ ctx, const float* __restrict__ ctx2,
    const float* __restrict__ Wfc, const float* __restrict__ lng,
    const float* __restrict__ lnb, float* __restrict__ out) {
  __shared__ __align__(16) float xs[16][292];  // stride 292: 16B-aligned
  __shared__ float red[16][4][2];
  const int tid = threadIdx.x;
  const int c = tid & 255;
  const int hf = tid >> 8;
  const int rbase = hf * 8;
  const int lane = tid & 63, wid = (tid >> 6) & 3;
  const int r0 = blockIdx.x * 16;

  for (int e = tid; e < 16 * 288; e += 512) {
    int r = e / 288, i = e - r * 288;
    xs[r][i] = (i < 256) ? ctx[(r0 + r) * 256 + i]
                         : ctx2[(r0 + r) * 32 + (i - 256)];
  }
  __syncthreads();

  float acc[8];
#pragma unroll
  for (int r = 0; r < 8; r++) acc[r] = 0.f;
  for (int i = 0; i < 288; i += 4) {
    float w0 = Wfc[i * 256 + c], w1 = Wfc[(i + 1) * 256 + c];
    float w2 = Wfc[(i + 2) * 256 + c], w3 = Wfc[(i + 3) * 256 + c];
#pragma unroll
    for (int r = 0; r < 8; r++) {
      float4 xv = *(const float4*)&xs[rbase + r][i];
      acc[r] += xv.x * w0 + xv.y * w1 + xv.z * w2 + xv.w * w3;
    }
  }

#pragma unroll
  for (int r = 0; r < 8; r++) {
    float s1 = acc[r], s2 = acc[r] * acc[r];
#pragma unroll
    for (int off = 32; off > 0; off >>= 1) {
      s1 += __shfl_xor(s1, off);
      s2 += __shfl_xor(s2, off);
    }
    if (lane == 0) {
      red[rbase + r][wid][0] = s1;
      red[rbase + r][wid][1] = s2;
    }
  }
  __syncthreads();

  float gt = lng[c], bt = lnb[c];
#pragma unroll
  for (int r = 0; r < 8; r++) {
    int row = rbase + r;
    float s1 = red[row][0][0] + red[row][1][0] + red[row][2][0] + red[row][3][0];
    float s2 = red[row][0][1] + red[row][1][1] + red[row][2][1] + red[row][3][1];
    float mu = s1 * (1.f / 256.f);
    float var = s2 * (1.f / 256.f) - mu * mu;
    float inv = rsqrtf(var + 1e-5f);
    out[(r0 + row) * 256 + c] = gt * (acc[r] - mu) * inv + bt;
  }
}

// ---------------------------------------------------------------------------
extern "C" void kernel_launch(void* const* d_in, const int* in_sizes, int n_in,
                              void* d_out, int out_size, void* d_ws,
                              size_t ws_size, hipStream_t stream) {
  const float* inQ = (const float*)d_in[0];
  const float* inK = (const float*)d_in[1];
  const float* inV = (const float*)d_in[2];
  const void* mask = d_in[3];
  const float* matrix = (const float*)d_in[4];
  const float* Wq = (const float*)d_in[5];
  const float* Wk = (const float*)d_in[6];
  const float* Wv = (const float*)d_in[7];
  const float* Wv2 = (const float*)d_in[8];
  const float* Wfc = (const float*)d_in[9];
  const float* lng = (const float*)d_in[10];
  const float* lnb = (const float*)d_in[11];
  const float* fulng = (const float*)d_in[12];
  const float* fulnb = (const float*)d_in[13];
  const float* fuw1 = (const float*)d_in[14];
  const float* fub1 = (const float*)d_in[15];
  const float* fuw2 = (const float*)d_in[16];
  const float* fub2 = (const float*)d_in[17];

  float* ws = (float*)d_ws;
  __hip_bfloat16* Qb = (__hip_bfloat16*)(ws + OFF_QB);
  __hip_bfloat16* Kb = (__hip_bfloat16*)(ws + OFF_KB);
  __hip_bfloat16* Vt = (__hip_bfloat16*)(ws + OFF_VT);
  float* Vp2 = ws + OFF_VP2;
  float* ctx = ws + OFF_CTX;
  float* ctx2 = ws + OFF_CTX2;
  __hip_bfloat16* gws = (__hip_bfloat16*)(ws + OFF_G);
  unsigned int* flag = (unsigned int*)(ws + OFF_FLAG);

  float* out = (float*)d_out;
  float* mout = out + BB * SS * DM;

  hipMemsetAsync(flag, 0, 4, stream);
  mask_or_kernel<<<64, 256, 0, stream>>>((const unsigned int*)mask, flag);
  proj_kernel<<<BB * SS / 16, 512, 0, stream>>>(inQ, inK, inV, Wq, Wk, Wv,
                                                Wv2, Qb, Kb, Vt, Vp2);
  attn_kernel<<<BB * (SS / 4), 512, 0, stream>>>(
      Qb, Kb, Vt, mask, matrix, fulng, fulnb, fuw1, fub1, fuw2, fub2, ctx,
      gws, flag);
  mout_kernel<<<BB * 64, 256, 0, stream>>>(matrix, gws, mout);
  ctx2_kernel<<<BB * (SS / 16), 256, 0, stream>>>(matrix, Vp2, ctx2);
  final_kernel<<<BB * SS / 16, 512, 0, stream>>>(ctx, ctx2, Wfc, lng, lnb,
                                                 out);
}

// Round 7
// 516.703 us; speedup vs baseline: 5.7802x; 1.1302x over previous
//
#include <hip/hip_runtime.h>
#include <hip/hip_bf16.h>

#define BB 16
#define SS 512
#define DM 256
#define NH 8

// workspace layout in float units
#define OFF_QB    0         // bf16 Q  [b,s,c]  2097152 elem
#define OFF_KB    1048576   // bf16 K  [b,s,c]
#define OFF_VT    2097152   // bf16 V^T [b,c,s]
#define OFF_VP2   3145728   // f32 [b,s,32]
#define OFF_CTXB  3407872   // bf16 ctx [b,s,256]
#define OFF_CTX2B 4456448   // bf16 ctx2 [b,s,32]
#define OFF_G     4587520   // bf16 g [b,q,k]
#define OFF_FLAG  6684672

#define SCALE 0.17677669529663687f

typedef __attribute__((ext_vector_type(8))) short bfrag8;  // 8 bf16 (4 VGPR)
typedef __attribute__((ext_vector_type(4))) float facc4;   // MFMA accumulator

// ---------------------------------------------------------------------------
// K0: OR-reduce first 64K words of the mask into *acc (acc pre-zeroed).
__global__ void mask_or_kernel(const unsigned int* __restrict__ w,
                               unsigned int* __restrict__ acc) {
  __shared__ unsigned int sh[256];
  unsigned int a = 0;
  int base = blockIdx.x * 1024;
  for (int i = threadIdx.x; i < 1024; i += 256) a |= w[base + i];
  sh[threadIdx.x] = a;
  __syncthreads();
  for (int s = 128; s > 0; s >>= 1) {
    if (threadIdx.x < s) sh[threadIdx.x] |= sh[threadIdx.x + s];
    __syncthreads();
  }
  if (threadIdx.x == 0) atomicOr(acc, sh[0]);
}

// ---------------------------------------------------------------------------
// K1: MFMA GEMM for the Q/K/V projections. One launch, 1536 blocks:
// matid = bid>>9 selects matrix; 64m x 64n tile per block, K=256 in 8 steps.
// Q/K written row-major bf16; V written transposed (Vt[b,c,s]) for AV B-frags.
// Rationale (r6): scalar proj was LDS-issue-bound (4 FMA per ds_read_b128);
// MFMA cuts LDS instructions ~16x.
__global__ __launch_bounds__(256) void gemm_qkv_kernel(
    const float* __restrict__ inQ, const float* __restrict__ inK,
    const float* __restrict__ inV,
    const float* __restrict__ Wq, const float* __restrict__ Wk,
    const float* __restrict__ Wv,
    __hip_bfloat16* __restrict__ Qb, __hip_bfloat16* __restrict__ Kb,
    __hip_bfloat16* __restrict__ Vt) {
  __shared__ __align__(16) __hip_bfloat16 As[64][40];  // [m][k] pad 40
  __shared__ __align__(16) __hip_bfloat16 Bs[64][40];  // [n][k] pad 40
  const int tid = threadIdx.x;
  const int bid = blockIdx.x;
  const int matid = bid >> 9;
  const int mblk = (bid & 511) >> 2;
  const int nblk = bid & 3;
  const int m0 = mblk * 64;
  const int n0 = nblk * 64;
  const float* X = (matid == 0) ? inQ : (matid == 1) ? inK : inV;
  const float* W = (matid == 0) ? Wq : (matid == 1) ? Wk : Wv;

  const int lane = tid & 63;
  const int w = tid >> 6;
  const int wm = w & 1, wn = w >> 1;
  const int cl = lane & 15, quad = lane >> 4;
  const int arow = tid >> 2, ak8 = (tid & 3) * 8;
  const int bn = tid & 63, bk8 = (tid >> 6) * 8;

  facc4 acc[2][2];
#pragma unroll
  for (int t = 0; t < 2; t++)
#pragma unroll
    for (int u = 0; u < 2; u++) acc[t][u] = (facc4){0.f, 0.f, 0.f, 0.f};

#pragma unroll 1
  for (int kc = 0; kc < 8; kc++) {
    // global loads first (overlap previous step's MFMAs)
    float4 x0 = *(const float4*)&X[(m0 + arow) * 256 + kc * 32 + ak8];
    float4 x1 = *(const float4*)&X[(m0 + arow) * 256 + kc * 32 + ak8 + 4];
    float wv[8];
#pragma unroll
    for (int j = 0; j < 8; j++) wv[j] = W[(kc * 32 + bk8 + j) * 256 + n0 + bn];
    __syncthreads();  // prior step's frag reads done
    {
      __hip_bfloat16 ta[8];
      ta[0] = __float2bfloat16(x0.x); ta[1] = __float2bfloat16(x0.y);
      ta[2] = __float2bfloat16(x0.z); ta[3] = __float2bfloat16(x0.w);
      ta[4] = __float2bfloat16(x1.x); ta[5] = __float2bfloat16(x1.y);
      ta[6] = __float2bfloat16(x1.z); ta[7] = __float2bfloat16(x1.w);
      *(uint4*)&As[arow][ak8] = *(uint4*)ta;
      __hip_bfloat16 tb[8];
#pragma unroll
      for (int j = 0; j < 8; j++) tb[j] = __float2bfloat16(wv[j]);
      *(uint4*)&Bs[bn][bk8] = *(uint4*)tb;
    }
    __syncthreads();
    bfrag8 aA[2], bB[2];
#pragma unroll
    for (int t = 0; t < 2; t++)
      aA[t] = *(const bfrag8*)&As[wm * 32 + t * 16 + cl][quad * 8];
#pragma unroll
    for (int u = 0; u < 2; u++)
      bB[u] = *(const bfrag8*)&Bs[wn * 32 + u * 16 + cl][quad * 8];
#pragma unroll
    for (int t = 0; t < 2; t++)
#pragma unroll
      for (int u = 0; u < 2; u++)
        acc[t][u] =
            __builtin_amdgcn_mfma_f32_16x16x32_bf16(aA[t], bB[u], acc[t][u], 0, 0, 0);
  }

  if (matid < 2) {
    __hip_bfloat16* Y = (matid == 0) ? Qb : Kb;
#pragma unroll
    for (int t = 0; t < 2; t++)
#pragma unroll
      for (int u = 0; u < 2; u++)
#pragma unroll
        for (int reg = 0; reg < 4; reg++)
          Y[(m0 + wm * 32 + t * 16 + quad * 4 + reg) * 256 + n0 + wn * 32 +
            u * 16 + cl] = __float2bfloat16(acc[t][u][reg]);
  } else {
#pragma unroll
    for (int t = 0; t < 2; t++)
#pragma unroll
      for (int u = 0; u < 2; u++) {
        int c = n0 + wn * 32 + u * 16 + cl;
        int mg = m0 + wm * 32 + t * 16 + quad * 4;
        int b = mg >> 9, s = mg & 511;
        __hip_bfloat16 pk[4];
#pragma unroll
        for (int reg = 0; reg < 4; reg++)
          pk[reg] = __float2bfloat16(acc[t][u][reg]);
        *(ushort4*)&Vt[(((b << 8) + c) << 9) + s] = *(ushort4*)pk;
      }
  }
}

// ---------------------------------------------------------------------------
// K1b: Vp2 = inV @ Wv2 (8192x32x256, tiny). 16 rows/block, grid 512.
__global__ __launch_bounds__(256) void vp2_kernel(
    const float* __restrict__ inV, const float* __restrict__ Wv2,
    float* __restrict__ Vp2) {
  __shared__ __align__(16) float xs[16][260];
  const int t = threadIdx.x;
  const int r0 = blockIdx.x * 16;
  for (int e = t; e < 16 * 256; e += 256) {
    int r = e >> 8, i = e & 255;
    xs[r][i] = inV[(r0 + r) * 256 + i];
  }
  __syncthreads();
  const int c2 = t & 31, rr = t >> 5;  // rr 0..7
  float a0 = 0.f, a1 = 0.f;
  for (int i = 0; i < 256; i += 4) {
    float w0 = Wv2[i * 32 + c2], w1 = Wv2[(i + 1) * 32 + c2];
    float w2 = Wv2[(i + 2) * 32 + c2], w3 = Wv2[(i + 3) * 32 + c2];
    float4 xa = *(const float4*)&xs[rr][i];
    float4 xb = *(const float4*)&xs[rr + 8][i];
    a0 += xa.x * w0 + xa.y * w1 + xa.z * w2 + xa.w * w3;
    a1 += xb.x * w0 + xb.y * w1 + xb.z * w2 + xb.w * w3;
  }
  Vp2[(r0 + rr) * 32 + c2] = a0;
  Vp2[(r0 + rr + 8) * 32 + c2] = a1;
}

// ---------------------------------------------------------------------------
// K2: fused scores(MFMA)+softmax+gate+AV(MFMA). 512 thr (wave=head),
// q-tile 8 (full-use of 8/16 MFMA rows, half the blocks of r6), grid 1024.
// Sb stride 520 (16B-aligned frags). Gate processed in half-chunks of 4 k
// to bound live registers (r4 spill lesson). ctx written bf16 for final GEMM.
__global__ __launch_bounds__(512) void attn_kernel(
    const __hip_bfloat16* __restrict__ Qb, const __hip_bfloat16* __restrict__ Kb,
    const __hip_bfloat16* __restrict__ Vt, const void* __restrict__ mask,
    const float* __restrict__ matrix,
    const float* __restrict__ fulng, const float* __restrict__ fulnb,
    const float* __restrict__ fuw1, const float* __restrict__ fub1,
    const float* __restrict__ fuw2, const float* __restrict__ fub2,
    __hip_bfloat16* __restrict__ ctxb, __hip_bfloat16* __restrict__ gws,
    const unsigned int* __restrict__ orv) {
  __shared__ __align__(16) __hip_bfloat16 Sb[NH][8][520];  // 66.6 KB
  __shared__ float fup[85];

  const int tid = threadIdx.x;
  const int lane = tid & 63;
  const int h = tid >> 6;
  const int cl = lane & 15;
  const int quad = lane >> 4;
  // XCD swizzle: 2 batches per XCD
  const int b = ((blockIdx.x & 7) << 1) | (blockIdx.x >> 9);
  const int q0 = ((blockIdx.x >> 3) & 63) * 8;

  if (tid < 9) fup[tid] = fulng[tid];
  else if (tid < 18) fup[tid] = fulnb[tid - 9];
  else if (tid < 72) fup[tid] = fuw1[tid - 18];
  else if (tid < 78) fup[tid] = fub1[tid - 72];
  else if (tid < 84) fup[tid] = fuw2[tid - 78];
  else if (tid == 84) fup[tid] = fub2[0];
  const unsigned int rawor = *orv;
  const int flagv = (rawor <= 1u) ? 0 : ((rawor == 0x3F800000u) ? 2 : 1);

  const int* mask_i = (const int*)mask;
  const unsigned char* mask_b = (const unsigned char*)mask;
  const float* mask_f = (const float*)mask;

  // ---- phase 1: raw scores via MFMA (8 real q rows) ----
  bfrag8 aQ = {0, 0, 0, 0, 0, 0, 0, 0};
  if (cl < 8)
    aQ = *(const bfrag8*)&Qb[(((b << 9) + q0 + cl) << 8) + h * 32 + quad * 8];
#pragma unroll 4
  for (int nt = 0; nt < 32; nt++) {
    bfrag8 bK =
        *(const bfrag8*)&Kb[(((b << 9) + nt * 16 + cl) << 8) + h * 32 + quad * 8];
    facc4 cacc = {0.f, 0.f, 0.f, 0.f};
    cacc = __builtin_amdgcn_mfma_f32_16x16x32_bf16(aQ, bK, cacc, 0, 0, 0);
    if (quad < 2) {  // rows 0..7 real
#pragma unroll
      for (int reg = 0; reg < 4; reg++)
        Sb[h][quad * 4 + reg][nt * 16 + cl] = __float2bfloat16(cacc[reg]);
    }
  }

  // ---- softmax (scale+mask; 8 rows per wave) ----
#pragma unroll 1
  for (int q = 0; q < 8; q++) {
    float v[8];
#pragma unroll
    for (int j = 0; j < 8; j++) {
      float raw = __bfloat162float(Sb[h][q][j * 64 + lane]) * SCALE;
      int midx = ((b * 8 + h) * 512 + q0 + q) * 512 + j * 64 + lane;
      bool m;
      if (flagv == 0) m = (mask_i[midx] != 0);
      else if (flagv == 1) m = (mask_b[midx] != 0);
      else m = (mask_f[midx] != 0.f);
      v[j] = m ? -1e9f : raw;
    }
    float mx = v[0];
#pragma unroll
    for (int j = 1; j < 8; j++) mx = fmaxf(mx, v[j]);
#pragma unroll
    for (int off = 32; off > 0; off >>= 1) mx = fmaxf(mx, __shfl_xor(mx, off));
    float sum = 0.f;
#pragma unroll
    for (int j = 0; j < 8; j++) {
      float e = __expf(v[j] - mx);
      v[j] = e;
      sum += e;
    }
#pragma unroll
    for (int off = 32; off > 0; off >>= 1) sum += __shfl_xor(sum, off);
    float inv = 1.f / sum;
#pragma unroll
    for (int j = 0; j < 8; j++)
      Sb[h][q][j * 64 + lane] = __float2bfloat16(v[j] * inv);
  }
  __syncthreads();  // all heads' probs visible

  // ---- gate: thread -> (gq, 8 k) in two halves of 4 ----
  {
    const int gq = tid >> 6;
    const int k0 = (tid & 63) * 8;
#pragma unroll 1
    for (int half = 0; half < 2; half++) {
      const int kh = k0 + half * 4;
      float4 mrow = *(const float4*)&matrix[((b << 9) + q0 + gq) * 512 + kh];
      float p[NH][4];
#pragma unroll
      for (int hh = 0; hh < NH; hh++) {
        ushort4 sv = *(const ushort4*)&Sb[hh][gq][kh];
        p[hh][0] = __bfloat162float(*(__hip_bfloat16*)&sv.x);
        p[hh][1] = __bfloat162float(*(__hip_bfloat16*)&sv.y);
        p[hh][2] = __bfloat162float(*(__hip_bfloat16*)&sv.z);
        p[hh][3] = __bfloat162float(*(__hip_bfloat16*)&sv.w);
      }
      const float mcomp[4] = {mrow.x, mrow.y, mrow.z, mrow.w};
      __hip_bfloat16 gout[4];
#pragma unroll
      for (int i = 0; i < 4; i++) {
        float v[9];
        v[0] = mcomp[i];
#pragma unroll
        for (int hh = 0; hh < NH; hh++) v[1 + hh] = p[hh][i];
        float mu = 0.f;
#pragma unroll
        for (int t = 0; t < 9; t++) mu += v[t];
        mu *= (1.f / 9.f);
        float var = 0.f;
#pragma unroll
        for (int t = 0; t < 9; t++) {
          float d = v[t] - mu;
          var += d * d;
        }
        var *= (1.f / 9.f);
        float inv = rsqrtf(var + 1e-5f);
        float y[9];
#pragma unroll
        for (int t = 0; t < 9; t++)
          y[t] = fup[t] * (v[t] - mu) * inv + fup[9 + t];
        float o = fup[84];
#pragma unroll
        for (int j = 0; j < 6; j++) {
          float z = fup[72 + j];
#pragma unroll
          for (int t = 0; t < 9; t++) z += y[t] * fup[18 + t * 6 + j];
          z = fmaxf(z, 0.f);
          o += z * fup[78 + j];
        }
        gout[i] = __float2bfloat16(1.f / (1.f + __expf(-o)));
      }
      *(ushort4*)&gws[((b << 9) + q0 + gq) * 512 + kh] = *(ushort4*)gout;
    }
  }

  // ---- AV via MFMA: A = probs (Sb, head-local), B = V^T from global ----
  facc4 a0 = {0.f, 0.f, 0.f, 0.f}, a1 = {0.f, 0.f, 0.f, 0.f};
#pragma unroll 2
  for (int kb = 0; kb < 16; kb++) {
    bfrag8 aP = {0, 0, 0, 0, 0, 0, 0, 0};
    if (cl < 8) aP = *(const bfrag8*)&Sb[h][cl][kb * 32 + quad * 8];
    bfrag8 b0 =
        *(const bfrag8*)&Vt[(((b << 8) + h * 32 + cl) << 9) + kb * 32 + quad * 8];
    bfrag8 b1 = *(const bfrag8*)&Vt[(((b << 8) + h * 32 + 16 + cl) << 9) +
                                    kb * 32 + quad * 8];
    a0 = __builtin_amdgcn_mfma_f32_16x16x32_bf16(aP, b0, a0, 0, 0, 0);
    a1 = __builtin_amdgcn_mfma_f32_16x16x32_bf16(aP, b1, a1, 0, 0, 0);
  }
  if (quad < 2) {
#pragma unroll
    for (int reg = 0; reg < 4; reg++) {
      int row = quad * 4 + reg;
      ctxb[((b << 9) + q0 + row) * 256 + h * 32 + cl] = __float2bfloat16(a0[reg]);
      ctxb[((b << 9) + q0 + row) * 256 + h * 32 + 16 + cl] =
          __float2bfloat16(a1[reg]);
    }
  }
}

// ---------------------------------------------------------------------------
// K3: mout[b,j,i] = matrix[b,j,i] * g[b,i,j]. 64x64 tiles, LDS transpose.
__global__ __launch_bounds__(256) void mout_kernel(
    const float* __restrict__ matrix, const __hip_bfloat16* __restrict__ g,
    float* __restrict__ mout) {
  __shared__ float Gs[64][65];
  const int tid = threadIdx.x;
  const int b = blockIdx.x >> 6;
  const int j0 = ((blockIdx.x >> 3) & 7) * 64;
  const int i0 = (blockIdx.x & 7) * 64;

  {
    int r = tid >> 2, c0 = (tid & 3) * 16;
    const __hip_bfloat16* gp = g + (((b << 9) + i0 + r) << 9) + j0 + c0;
    ushort us[16];
    *(uint4*)(us) = *(const uint4*)(gp);
    *(uint4*)(us + 8) = *(const uint4*)(gp + 8);
#pragma unroll
    for (int k = 0; k < 16; k++) {
      __hip_bfloat16 hv = *(__hip_bfloat16*)&us[k];
      Gs[r][c0 + k] = __bfloat162float(hv);
    }
  }
  __syncthreads();

  {
    int jj = tid >> 2, ic = (tid & 3) * 16;
    const float* mp = matrix + (((b << 9) + j0 + jj) << 9) + i0 + ic;
    float* op = mout + (((b << 9) + j0 + jj) << 9) + i0 + ic;
#pragma unroll
    for (int v4 = 0; v4 < 4; v4++) {
      float4 m = *(const float4*)(mp + v4 * 4);
      float4 o;
      o.x = m.x * Gs[ic + v4 * 4 + 0][jj];
      o.y = m.y * Gs[ic + v4 * 4 + 1][jj];
      o.z = m.z * Gs[ic + v4 * 4 + 2][jj];
      o.w = m.w * Gs[ic + v4 * 4 + 3][jj];
      *(float4*)(op + v4 * 4) = o;
    }
  }
}

// ---------------------------------------------------------------------------
// K4: ctx2b[b,s,dv] (bf16) = sum_k matrix[b,s,k] * Vp2[b,k,dv]. Grid 512.
__global__ __launch_bounds__(256) void ctx2_kernel(
    const float* __restrict__ matrix, const float* __restrict__ Vp2,
    __hip_bfloat16* __restrict__ ctx2b) {
  __shared__ __align__(16) float Ms[16][128];
  __shared__ __align__(16) float Vs2t[32][132];
  const int t = threadIdx.x;
  const int b = blockIdx.x >> 5;
  const int s0 = (blockIdx.x & 31) * 16;
  const int dv = t & 31, rg = t >> 5;
  float acc0 = 0.f, acc1 = 0.f;
  for (int kc = 0; kc < 4; kc++) {
    __syncthreads();
#pragma unroll
    for (int it = 0; it < 8; it++) {
      int idx = t + it * 256;
      int r = idx >> 7, cc = idx & 127;
      Ms[r][cc] = matrix[((b << 9) + s0 + r) * 512 + kc * 128 + cc];
    }
#pragma unroll
    for (int it = 0; it < 16; it++) {
      int e = t + it * 256;
      int k = e >> 5, dv2 = e & 31;
      Vs2t[dv2][k] = Vp2[((b << 9) + kc * 128 + k) * 32 + dv2];
    }
    __syncthreads();
    for (int k = 0; k < 128; k += 4) {
      float4 vv = *(const float4*)&Vs2t[dv][k];
      float4 m0 = *(const float4*)&Ms[rg][k];
      float4 m1 = *(const float4*)&Ms[rg + 8][k];
      acc0 += m0.x * vv.x + m0.y * vv.y + m0.z * vv.z + m0.w * vv.w;
      acc1 += m1.x * vv.x + m1.y * vv.y + m1.z * vv.z + m1.w * vv.w;
    }
  }
  ctx2b[((b << 9) + s0 + rg) * 32 + dv] = __float2bfloat16(acc0);
  ctx2b[((b << 9) + s0 + rg + 8) * 32 + dv] = __float2bfloat16(acc1);
}

// ---------------------------------------------------------------------------
// K5: out = LN([ctxb|ctx2b] @ Wfc). MFMA GEMM 32m x 256n, K=288 (9 steps),
// LDS LayerNorm epilogue. Grid 256, 256 thr.
__global__ __launch_bounds__(256) void final_kernel(
    const __hip_bfloat16* __restrict__ ctxb,
    const __hip_bfloat16* __restrict__ ctx2b, const float* __restrict__ Wfc,
    const float* __restrict__ lng, const float* __restrict__ lnb,
    float* __restrict__ out) {
  __shared__ __align__(16) __hip_bfloat16 As[32][40];
  __shared__ __align__(16) __hip_bfloat16 Bs[256][40];
  __shared__ __align__(16) float xs[32][260];
  __shared__ float red2[32][8][2];
  __shared__ float musig[32][2];
  const int tid = threadIdx.x;
  const int m0 = blockIdx.x * 32;
  const int lane = tid & 63, w = tid >> 6;
  const int cl = lane & 15, quad = lane >> 4;
  const int arow = tid >> 3, ak4 = (tid & 7) * 4;

  facc4 acc[2][4];
#pragma unroll
  for (int t = 0; t < 2; t++)
#pragma unroll
    for (int u = 0; u < 4; u++) acc[t][u] = (facc4){0.f, 0.f, 0.f, 0.f};

#pragma unroll 1
  for (int kc = 0; kc < 9; kc++) {
    ushort4 av;
    if (kc < 8)
      av = *(const ushort4*)&ctxb[(m0 + arow) * 256 + kc * 32 + ak4];
    else
      av = *(const ushort4*)&ctx2b[(m0 + arow) * 32 + ak4];
    float wv[32];
#pragma unroll
    for (int j = 0; j < 32; j++) wv[j] = Wfc[(kc * 32 + j) * 256 + tid];
    __syncthreads();
    *(ushort4*)&As[arow][ak4] = av;
    {
      __hip_bfloat16 tw[32];
#pragma unroll
      for (int j = 0; j < 32; j++) tw[j] = __float2bfloat16(wv[j]);
#pragma unroll
      for (int g = 0; g < 4; g++) *(uint4*)&Bs[tid][g * 8] = *(uint4*)&tw[g * 8];
    }
    __syncthreads();
    bfrag8 aA[2], bB[4];
#pragma unroll
    for (int t = 0; t < 2; t++)
      aA[t] = *(const bfrag8*)&As[t * 16 + cl][quad * 8];
#pragma unroll
    for (int u = 0; u < 4; u++)
      bB[u] = *(const bfrag8*)&Bs[w * 64 + u * 16 + cl][quad * 8];
#pragma unroll
    for (int t = 0; t < 2; t++)
#pragma unroll
      for (int u = 0; u < 4; u++)
        acc[t][u] =
            __builtin_amdgcn_mfma_f32_16x16x32_bf16(aA[t], bB[u], acc[t][u], 0, 0, 0);
  }

  // dump C to LDS for the LN
#pragma unroll
  for (int t = 0; t < 2; t++)
#pragma unroll
    for (int u = 0; u < 4; u++)
#pragma unroll
      for (int reg = 0; reg < 4; reg++)
        xs[t * 16 + quad * 4 + reg][w * 64 + u * 16 + cl] = acc[t][u][reg];
  __syncthreads();

  // LN pass1: partial sums (8 threads per row)
  {
    int r = tid >> 3, c0 = (tid & 7) * 32;
    float s1 = 0.f, s2 = 0.f;
    for (int j = 0; j < 32; j += 4) {
      float4 v = *(const float4*)&xs[r][c0 + j];
      s1 += v.x + v.y + v.z + v.w;
      s2 += v.x * v.x + v.y * v.y + v.z * v.z + v.w * v.w;
    }
    red2[r][tid & 7][0] = s1;
    red2[r][tid & 7][1] = s2;
  }
  __syncthreads();
  if (tid < 32) {
    float s1 = 0.f, s2 = 0.f;
#pragma unroll
    for (int j = 0; j < 8; j++) {
      s1 += red2[tid][j][0];
      s2 += red2[tid][j][1];
    }
    float mu = s1 * (1.f / 256.f);
    float var = s2 * (1.f / 256.f) - mu * mu;
    musig[tid][0] = mu;
    musig[tid][1] = rsqrtf(var + 1e-5f);
  }
  __syncthreads();
  {
    float gt = lng[tid], bt = lnb[tid];
#pragma unroll 4
    for (int r = 0; r < 32; r++)
      out[(m0 + r) * 256 + tid] =
          gt * (xs[r][tid] - musig[r][0]) * musig[r][1] + bt;
  }
}

// ---------------------------------------------------------------------------
extern "C" void kernel_launch(void* const* d_in, const int* in_sizes, int n_in,
                              void* d_out, int out_size, void* d_ws,
                              size_t ws_size, hipStream_t stream) {
  const float* inQ = (const float*)d_in[0];
  const float* inK = (const float*)d_in[1];
  const float* inV = (const float*)d_in[2];
  const void* mask = d_in[3];
  const float* matrix = (const float*)d_in[4];
  const float* Wq = (const float*)d_in[5];
  const float* Wk = (const float*)d_in[6];
  const float* Wv = (const float*)d_in[7];
  const float* Wv2 = (const float*)d_in[8];
  const float* Wfc = (const float*)d_in[9];
  const float* lng = (const float*)d_in[10];
  const float* lnb = (const float*)d_in[11];
  const float* fulng = (const float*)d_in[12];
  const float* fulnb = (const float*)d_in[13];
  const float* fuw1 = (const float*)d_in[14];
  const float* fub1 = (const float*)d_in[15];
  const float* fuw2 = (const float*)d_in[16];
  const float* fub2 = (const float*)d_in[17];

  float* ws = (float*)d_ws;
  __hip_bfloat16* Qb = (__hip_bfloat16*)(ws + OFF_QB);
  __hip_bfloat16* Kb = (__hip_bfloat16*)(ws + OFF_KB);
  __hip_bfloat16* Vt = (__hip_bfloat16*)(ws + OFF_VT);
  float* Vp2 = ws + OFF_VP2;
  __hip_bfloat16* ctxb = (__hip_bfloat16*)(ws + OFF_CTXB);
  __hip_bfloat16* ctx2b = (__hip_bfloat16*)(ws + OFF_CTX2B);
  __hip_bfloat16* gws = (__hip_bfloat16*)(ws + OFF_G);
  unsigned int* flag = (unsigned int*)(ws + OFF_FLAG);

  float* out = (float*)d_out;
  float* mout = out + BB * SS * DM;

  hipMemsetAsync(flag, 0, 4, stream);
  mask_or_kernel<<<64, 256, 0, stream>>>((const unsigned int*)mask, flag);
  gemm_qkv_kernel<<<1536, 256, 0, stream>>>(inQ, inK, inV, Wq, Wk, Wv, Qb, Kb,
                                            Vt);
  vp2_kernel<<<512, 256, 0, stream>>>(inV, Wv2, Vp2);
  attn_kernel<<<1024, 512, 0, stream>>>(Qb, Kb, Vt, mask, matrix, fulng,
                                        fulnb, fuw1, fub1, fuw2, fub2, ctxb,
                                        gws, flag);
  mout_kernel<<<BB * 64, 256, 0, stream>>>(matrix, gws, mout);
  ctx2_kernel<<<512, 256, 0, stream>>>(matrix, Vp2, ctx2b);
  final_kernel<<<256, 256, 0, stream>>>(ctxb, ctx2b, Wfc, lng, lnb, out);
}

// Round 8
// 463.688 us; speedup vs baseline: 6.4410x; 1.1143x over previous
//
#include <hip/hip_runtime.h>
#include <hip/hip_bf16.h>

#define BB 16
#define SS 512
#define DM 256
#define NH 8

// workspace layout in float units
#define OFF_QB    0         // bf16 Q  [b,s,c]  2097152 elem
#define OFF_KB    1048576   // bf16 K  [b,s,c]
#define OFF_VT    2097152   // bf16 V^T [b,c,s]
#define OFF_VP2   3145728   // f32 [b,s,32]
#define OFF_CTXB  3407872   // bf16 ctx [b,s,256]
#define OFF_CTX2B 4456448   // bf16 ctx2 [b,s,32]
#define OFF_G     4587520   // bf16 g [b,q,k]
#define OFF_FLAG  6684672

#define SCALE 0.17677669529663687f

typedef __attribute__((ext_vector_type(8))) short bfrag8;  // 8 bf16 (4 VGPR)
typedef __attribute__((ext_vector_type(4))) float facc4;   // MFMA accumulator

// ---------------------------------------------------------------------------
// K0: OR-reduce first 64K words of the mask into *acc (acc pre-zeroed).
__global__ void mask_or_kernel(const unsigned int* __restrict__ w,
                               unsigned int* __restrict__ acc) {
  __shared__ unsigned int sh[256];
  unsigned int a = 0;
  int base = blockIdx.x * 1024;
  for (int i = threadIdx.x; i < 1024; i += 256) a |= w[base + i];
  sh[threadIdx.x] = a;
  __syncthreads();
  for (int s = 128; s > 0; s >>= 1) {
    if (threadIdx.x < s) sh[threadIdx.x] |= sh[threadIdx.x + s];
    __syncthreads();
  }
  if (threadIdx.x == 0) atomicOr(acc, sh[0]);
}

// ---------------------------------------------------------------------------
// K1: MFMA GEMM for Q/K/V projections (unchanged from r7 — works).
__global__ __launch_bounds__(256) void gemm_qkv_kernel(
    const float* __restrict__ inQ, const float* __restrict__ inK,
    const float* __restrict__ inV,
    const float* __restrict__ Wq, const float* __restrict__ Wk,
    const float* __restrict__ Wv,
    __hip_bfloat16* __restrict__ Qb, __hip_bfloat16* __restrict__ Kb,
    __hip_bfloat16* __restrict__ Vt) {
  __shared__ __align__(16) __hip_bfloat16 As[64][40];
  __shared__ __align__(16) __hip_bfloat16 Bs[64][40];
  const int tid = threadIdx.x;
  const int bid = blockIdx.x;
  const int matid = bid >> 9;
  const int mblk = (bid & 511) >> 2;
  const int nblk = bid & 3;
  const int m0 = mblk * 64;
  const int n0 = nblk * 64;
  const float* X = (matid == 0) ? inQ : (matid == 1) ? inK : inV;
  const float* W = (matid == 0) ? Wq : (matid == 1) ? Wk : Wv;

  const int lane = tid & 63;
  const int w = tid >> 6;
  const int wm = w & 1, wn = w >> 1;
  const int cl = lane & 15, quad = lane >> 4;
  const int arow = tid >> 2, ak8 = (tid & 3) * 8;
  const int bn = tid & 63, bk8 = (tid >> 6) * 8;

  facc4 acc[2][2];
#pragma unroll
  for (int t = 0; t < 2; t++)
#pragma unroll
    for (int u = 0; u < 2; u++) acc[t][u] = (facc4){0.f, 0.f, 0.f, 0.f};

#pragma unroll 1
  for (int kc = 0; kc < 8; kc++) {
    float4 x0 = *(const float4*)&X[(m0 + arow) * 256 + kc * 32 + ak8];
    float4 x1 = *(const float4*)&X[(m0 + arow) * 256 + kc * 32 + ak8 + 4];
    float wv[8];
#pragma unroll
    for (int j = 0; j < 8; j++) wv[j] = W[(kc * 32 + bk8 + j) * 256 + n0 + bn];
    __syncthreads();
    {
      __hip_bfloat16 ta[8];
      ta[0] = __float2bfloat16(x0.x); ta[1] = __float2bfloat16(x0.y);
      ta[2] = __float2bfloat16(x0.z); ta[3] = __float2bfloat16(x0.w);
      ta[4] = __float2bfloat16(x1.x); ta[5] = __float2bfloat16(x1.y);
      ta[6] = __float2bfloat16(x1.z); ta[7] = __float2bfloat16(x1.w);
      *(uint4*)&As[arow][ak8] = *(uint4*)ta;
      __hip_bfloat16 tb[8];
#pragma unroll
      for (int j = 0; j < 8; j++) tb[j] = __float2bfloat16(wv[j]);
      *(uint4*)&Bs[bn][bk8] = *(uint4*)tb;
    }
    __syncthreads();
    bfrag8 aA[2], bB[2];
#pragma unroll
    for (int t = 0; t < 2; t++)
      aA[t] = *(const bfrag8*)&As[wm * 32 + t * 16 + cl][quad * 8];
#pragma unroll
    for (int u = 0; u < 2; u++)
      bB[u] = *(const bfrag8*)&Bs[wn * 32 + u * 16 + cl][quad * 8];
#pragma unroll
    for (int t = 0; t < 2; t++)
#pragma unroll
      for (int u = 0; u < 2; u++)
        acc[t][u] =
            __builtin_amdgcn_mfma_f32_16x16x32_bf16(aA[t], bB[u], acc[t][u], 0, 0, 0);
  }

  if (matid < 2) {
    __hip_bfloat16* Y = (matid == 0) ? Qb : Kb;
#pragma unroll
    for (int t = 0; t < 2; t++)
#pragma unroll
      for (int u = 0; u < 2; u++)
#pragma unroll
        for (int reg = 0; reg < 4; reg++)
          Y[(m0 + wm * 32 + t * 16 + quad * 4 + reg) * 256 + n0 + wn * 32 +
            u * 16 + cl] = __float2bfloat16(acc[t][u][reg]);
  } else {
#pragma unroll
    for (int t = 0; t < 2; t++)
#pragma unroll
      for (int u = 0; u < 2; u++) {
        int c = n0 + wn * 32 + u * 16 + cl;
        int mg = m0 + wm * 32 + t * 16 + quad * 4;
        int b = mg >> 9, s = mg & 511;
        __hip_bfloat16 pk[4];
#pragma unroll
        for (int reg = 0; reg < 4; reg++)
          pk[reg] = __float2bfloat16(acc[t][u][reg]);
        *(ushort4*)&Vt[(((b << 8) + c) << 9) + s] = *(ushort4*)pk;
      }
  }
}

// ---------------------------------------------------------------------------
// K1b: Vp2 = inV @ Wv2 (unchanged).
__global__ __launch_bounds__(256) void vp2_kernel(
    const float* __restrict__ inV, const float* __restrict__ Wv2,
    float* __restrict__ Vp2) {
  __shared__ __align__(16) float xs[16][260];
  const int t = threadIdx.x;
  const int r0 = blockIdx.x * 16;
  for (int e = t; e < 16 * 256; e += 256) {
    int r = e >> 8, i = e & 255;
    xs[r][i] = inV[(r0 + r) * 256 + i];
  }
  __syncthreads();
  const int c2 = t & 31, rr = t >> 5;
  float a0 = 0.f, a1 = 0.f;
  for (int i = 0; i < 256; i += 4) {
    float w0 = Wv2[i * 32 + c2], w1 = Wv2[(i + 1) * 32 + c2];
    float w2 = Wv2[(i + 2) * 32 + c2], w3 = Wv2[(i + 3) * 32 + c2];
    float4 xa = *(const float4*)&xs[rr][i];
    float4 xb = *(const float4*)&xs[rr + 8][i];
    a0 += xa.x * w0 + xa.y * w1 + xa.z * w2 + xa.w * w3;
    a1 += xb.x * w0 + xb.y * w1 + xb.z * w2 + xb.w * w3;
  }
  Vp2[(r0 + rr) * 32 + c2] = a0;
  Vp2[(r0 + rr + 8) * 32 + c2] = a1;
}

// ---------------------------------------------------------------------------
// K2: flash-style fused attention. Block = 512 thr (wave = head), 16 q rows,
// grid 512. THREE passes over k via MFMA recompute (scores are never stored):
//   P1: row maxes (mask skipped — unmasked max is a valid stability shift).
//   P2: row sums (mask applied at exp: masked -> 0 contribution).
//   P3: per 128-k chunk: normalized probs -> LDS -> gate (all heads) + AV MFMA.
// Per-lane state ~25 scalars, statically indexed -> spill-proof (r1-r4 lesson).
__global__ __launch_bounds__(512) void attn_kernel(
    const __hip_bfloat16* __restrict__ Qb, const __hip_bfloat16* __restrict__ Kb,
    const __hip_bfloat16* __restrict__ Vt, const void* __restrict__ mask,
    const float* __restrict__ matrix,
    const float* __restrict__ fulng, const float* __restrict__ fulnb,
    const float* __restrict__ fuw1, const float* __restrict__ fub1,
    const float* __restrict__ fuw2, const float* __restrict__ fub2,
    __hip_bfloat16* __restrict__ ctxb, __hip_bfloat16* __restrict__ gws,
    const unsigned int* __restrict__ orv) {
  __shared__ __align__(16) __hip_bfloat16 Sb[NH][16][136];  // 34.8 KB, 2-way banks
  __shared__ float fup[85];

  const int tid = threadIdx.x;
  const int lane = tid & 63;
  const int h = tid >> 6;
  const int cl = lane & 15, quad = lane >> 4;
  // XCD swizzle: 2 batches per XCD
  const int b = ((blockIdx.x & 7) << 1) | (blockIdx.x >> 8);
  const int q0 = ((blockIdx.x >> 3) & 31) * 16;

  if (tid < 9) fup[tid] = fulng[tid];
  else if (tid < 18) fup[tid] = fulnb[tid - 9];
  else if (tid < 72) fup[tid] = fuw1[tid - 18];
  else if (tid < 78) fup[tid] = fub1[tid - 72];
  else if (tid < 84) fup[tid] = fuw2[tid - 78];
  else if (tid == 84) fup[tid] = fub2[0];
  const unsigned int rawor = *orv;
  const int flagv = (rawor <= 1u) ? 0 : ((rawor == 0x3F800000u) ? 2 : 1);

  const unsigned char* mask_b = (const unsigned char*)mask;
  const int* mask_i = (const int*)mask;
  const float* mask_f = (const float*)mask;
  const int mbase = ((b * 8 + h) * 512 + q0) * 512;

  // A-frag: 16 real q rows (full M utilization)
  const bfrag8 aQ =
      *(const bfrag8*)&Qb[(((b << 9) + q0 + cl) << 8) + h * 32 + quad * 8];
  const __hip_bfloat16* KbB = &Kb[((b << 9) << 8) + h * 32 + quad * 8];
  const __hip_bfloat16* VtB = &Vt[(((b << 8) + h * 32) << 9)];

  // ---- pass 1: row maxes ----
  float mx[4] = {-3e38f, -3e38f, -3e38f, -3e38f};
#pragma unroll 4
  for (int nt = 0; nt < 32; nt++) {
    bfrag8 bK = *(const bfrag8*)&KbB[(nt * 16 + cl) << 8];
    facc4 cc = {0.f, 0.f, 0.f, 0.f};
    cc = __builtin_amdgcn_mfma_f32_16x16x32_bf16(aQ, bK, cc, 0, 0, 0);
#pragma unroll
    for (int r = 0; r < 4; r++) mx[r] = fmaxf(mx[r], cc[r]);
  }
#pragma unroll
  for (int r = 0; r < 4; r++)
#pragma unroll
    for (int off = 1; off <= 8; off <<= 1)
      mx[r] = fmaxf(mx[r], __shfl_xor(mx[r], off));

  // ---- pass 2: row sums (mask applied at exp) ----
  float l[4] = {0.f, 0.f, 0.f, 0.f};
#pragma unroll 2
  for (int nt = 0; nt < 32; nt++) {
    bfrag8 bK = *(const bfrag8*)&KbB[(nt * 16 + cl) << 8];
    facc4 cc = {0.f, 0.f, 0.f, 0.f};
    cc = __builtin_amdgcn_mfma_f32_16x16x32_bf16(aQ, bK, cc, 0, 0, 0);
#pragma unroll
    for (int r = 0; r < 4; r++) {
      int midx = mbase + (quad * 4 + r) * 512 + nt * 16 + cl;
      bool m;
      if (flagv == 1) m = (mask_b[midx] != 0);
      else if (flagv == 0) m = (mask_i[midx] != 0);
      else m = (mask_f[midx] != 0.f);
      float e = m ? 0.f : __expf(SCALE * (cc[r] - mx[r]));
      l[r] += e;
    }
  }
#pragma unroll
  for (int r = 0; r < 4; r++)
#pragma unroll
    for (int off = 1; off <= 8; off <<= 1) l[r] += __shfl_xor(l[r], off);
  float invl[4];
#pragma unroll
  for (int r = 0; r < 4; r++) invl[r] = 1.f / l[r];

  // ---- pass 3: per 128-k chunk: probs->LDS, gate + AV ----
  facc4 a0 = {0.f, 0.f, 0.f, 0.f}, a1 = {0.f, 0.f, 0.f, 0.f};
#pragma unroll 1
  for (int c = 0; c < 4; c++) {
    if (c) __syncthreads();  // prev chunk's gate/AV reads done
#pragma unroll 2
    for (int nt = c * 8; nt < c * 8 + 8; nt++) {
      bfrag8 bK = *(const bfrag8*)&KbB[(nt * 16 + cl) << 8];
      facc4 cc = {0.f, 0.f, 0.f, 0.f};
      cc = __builtin_amdgcn_mfma_f32_16x16x32_bf16(aQ, bK, cc, 0, 0, 0);
#pragma unroll
      for (int r = 0; r < 4; r++) {
        int midx = mbase + (quad * 4 + r) * 512 + nt * 16 + cl;
        bool m;
        if (flagv == 1) m = (mask_b[midx] != 0);
        else if (flagv == 0) m = (mask_i[midx] != 0);
        else m = (mask_f[midx] != 0.f);
        float e = m ? 0.f : __expf(SCALE * (cc[r] - mx[r]));
        Sb[h][quad * 4 + r][nt * 16 + cl - c * 128] =
            __float2bfloat16(e * invl[r]);
      }
    }
    __syncthreads();  // probs of all heads visible (also covers fup, c=0)

    // gate: thread -> (gq, 4 consecutive k in this chunk)
    {
      const int gq = tid >> 5;
      const int k4 = (tid & 31) * 4;
      float4 mrow =
          *(const float4*)&matrix[((b << 9) + q0 + gq) * 512 + c * 128 + k4];
      float p[NH][4];
#pragma unroll
      for (int hh = 0; hh < NH; hh++) {
        ushort4 sv = *(const ushort4*)&Sb[hh][gq][k4];
        p[hh][0] = __bfloat162float(*(__hip_bfloat16*)&sv.x);
        p[hh][1] = __bfloat162float(*(__hip_bfloat16*)&sv.y);
        p[hh][2] = __bfloat162float(*(__hip_bfloat16*)&sv.z);
        p[hh][3] = __bfloat162float(*(__hip_bfloat16*)&sv.w);
      }
      const float mcomp[4] = {mrow.x, mrow.y, mrow.z, mrow.w};
      __hip_bfloat16 gout[4];
#pragma unroll
      for (int i = 0; i < 4; i++) {
        float v[9];
        v[0] = mcomp[i];
#pragma unroll
        for (int t = 0; t < NH; t++) v[1 + t] = p[t][i];
        float mu = 0.f;
#pragma unroll
        for (int t = 0; t < 9; t++) mu += v[t];
        mu *= (1.f / 9.f);
        float var = 0.f;
#pragma unroll
        for (int t = 0; t < 9; t++) {
          float d = v[t] - mu;
          var += d * d;
        }
        var *= (1.f / 9.f);
        float inv = rsqrtf(var + 1e-5f);
        float y[9];
#pragma unroll
        for (int t = 0; t < 9; t++)
          y[t] = fup[t] * (v[t] - mu) * inv + fup[9 + t];
        float o = fup[84];
#pragma unroll
        for (int j = 0; j < 6; j++) {
          float z = fup[72 + j];
#pragma unroll
          for (int t = 0; t < 9; t++) z += y[t] * fup[18 + t * 6 + j];
          z = fmaxf(z, 0.f);
          o += z * fup[78 + j];
        }
        gout[i] = __float2bfloat16(1.f / (1.f + __expf(-o)));
      }
      *(ushort4*)&gws[((b << 9) + q0 + gq) * 512 + c * 128 + k4] =
          *(ushort4*)gout;
    }

    // AV for this chunk: A-frags from Sb (own head), B from Vt
#pragma unroll
    for (int ks = 0; ks < 4; ks++) {
      bfrag8 aP = *(const bfrag8*)&Sb[h][cl][ks * 32 + quad * 8];
      bfrag8 b0 =
          *(const bfrag8*)&VtB[(cl << 9) + c * 128 + ks * 32 + quad * 8];
      bfrag8 b1 =
          *(const bfrag8*)&VtB[((16 + cl) << 9) + c * 128 + ks * 32 + quad * 8];
      a0 = __builtin_amdgcn_mfma_f32_16x16x32_bf16(aP, b0, a0, 0, 0, 0);
      a1 = __builtin_amdgcn_mfma_f32_16x16x32_bf16(aP, b1, a1, 0, 0, 0);
    }
  }

#pragma unroll
  for (int r = 0; r < 4; r++) {
    int row = quad * 4 + r;
    ctxb[((b << 9) + q0 + row) * 256 + h * 32 + cl] = __float2bfloat16(a0[r]);
    ctxb[((b << 9) + q0 + row) * 256 + h * 32 + 16 + cl] =
        __float2bfloat16(a1[r]);
  }
}

// ---------------------------------------------------------------------------
// K3: mout[b,j,i] = matrix[b,j,i] * g[b,i,j] (unchanged).
__global__ __launch_bounds__(256) void mout_kernel(
    const float* __restrict__ matrix, const __hip_bfloat16* __restrict__ g,
    float* __restrict__ mout) {
  __shared__ float Gs[64][65];
  const int tid = threadIdx.x;
  const int b = blockIdx.x >> 6;
  const int j0 = ((blockIdx.x >> 3) & 7) * 64;
  const int i0 = (blockIdx.x & 7) * 64;

  {
    int r = tid >> 2, c0 = (tid & 3) * 16;
    const __hip_bfloat16* gp = g + (((b << 9) + i0 + r) << 9) + j0 + c0;
    ushort us[16];
    *(uint4*)(us) = *(const uint4*)(gp);
    *(uint4*)(us + 8) = *(const uint4*)(gp + 8);
#pragma unroll
    for (int k = 0; k < 16; k++) {
      __hip_bfloat16 hv = *(__hip_bfloat16*)&us[k];
      Gs[r][c0 + k] = __bfloat162float(hv);
    }
  }
  __syncthreads();

  {
    int jj = tid >> 2, ic = (tid & 3) * 16;
    const float* mp = matrix + (((b << 9) + j0 + jj) << 9) + i0 + ic;
    float* op = mout + (((b << 9) + j0 + jj) << 9) + i0 + ic;
#pragma unroll
    for (int v4 = 0; v4 < 4; v4++) {
      float4 m = *(const float4*)(mp + v4 * 4);
      float4 o;
      o.x = m.x * Gs[ic + v4 * 4 + 0][jj];
      o.y = m.y * Gs[ic + v4 * 4 + 1][jj];
      o.z = m.z * Gs[ic + v4 * 4 + 2][jj];
      o.w = m.w * Gs[ic + v4 * 4 + 3][jj];
      *(float4*)(op + v4 * 4) = o;
    }
  }
}

// ---------------------------------------------------------------------------
// K4: ctx2b = matrix @ Vp2 (unchanged).
__global__ __launch_bounds__(256) void ctx2_kernel(
    const float* __restrict__ matrix, const float* __restrict__ Vp2,
    __hip_bfloat16* __restrict__ ctx2b) {
  __shared__ __align__(16) float Ms[16][128];
  __shared__ __align__(16) float Vs2t[32][132];
  const int t = threadIdx.x;
  const int b = blockIdx.x >> 5;
  const int s0 = (blockIdx.x & 31) * 16;
  const int dv = t & 31, rg = t >> 5;
  float acc0 = 0.f, acc1 = 0.f;
  for (int kc = 0; kc < 4; kc++) {
    __syncthreads();
#pragma unroll
    for (int it = 0; it < 8; it++) {
      int idx = t + it * 256;
      int r = idx >> 7, cc = idx & 127;
      Ms[r][cc] = matrix[((b << 9) + s0 + r) * 512 + kc * 128 + cc];
    }
#pragma unroll
    for (int it = 0; it < 16; it++) {
      int e = t + it * 256;
      int k = e >> 5, dv2 = e & 31;
      Vs2t[dv2][k] = Vp2[((b << 9) + kc * 128 + k) * 32 + dv2];
    }
    __syncthreads();
    for (int k = 0; k < 128; k += 4) {
      float4 vv = *(const float4*)&Vs2t[dv][k];
      float4 m0 = *(const float4*)&Ms[rg][k];
      float4 m1 = *(const float4*)&Ms[rg + 8][k];
      acc0 += m0.x * vv.x + m0.y * vv.y + m0.z * vv.z + m0.w * vv.w;
      acc1 += m1.x * vv.x + m1.y * vv.y + m1.z * vv.z + m1.w * vv.w;
    }
  }
  ctx2b[((b << 9) + s0 + rg) * 32 + dv] = __float2bfloat16(acc0);
  ctx2b[((b << 9) + s0 + rg + 8) * 32 + dv] = __float2bfloat16(acc1);
}

// ---------------------------------------------------------------------------
// K5: out = LN([ctxb|ctx2b] @ Wfc) (unchanged).
__global__ __launch_bounds__(256) void final_kernel(
    const __hip_bfloat16* __restrict__ ctxb,
    const __hip_bfloat16* __restrict__ ctx2b, const float* __restrict__ Wfc,
    const float* __restrict__ lng, const float* __restrict__ lnb,
    float* __restrict__ out) {
  __shared__ __align__(16) __hip_bfloat16 As[32][40];
  __shared__ __align__(16) __hip_bfloat16 Bs[256][40];
  __shared__ __align__(16) float xs[32][260];
  __shared__ float red2[32][8][2];
  __shared__ float musig[32][2];
  const int tid = threadIdx.x;
  const int m0 = blockIdx.x * 32;
  const int lane = tid & 63, w = tid >> 6;
  const int cl = lane & 15, quad = lane >> 4;
  const int arow = tid >> 3, ak4 = (tid & 7) * 4;

  facc4 acc[2][4];
#pragma unroll
  for (int t = 0; t < 2; t++)
#pragma unroll
    for (int u = 0; u < 4; u++) acc[t][u] = (facc4){0.f, 0.f, 0.f, 0.f};

#pragma unroll 1
  for (int kc = 0; kc < 9; kc++) {
    ushort4 av;
    if (kc < 8)
      av = *(const ushort4*)&ctxb[(m0 + arow) * 256 + kc * 32 + ak4];
    else
      av = *(const ushort4*)&ctx2b[(m0 + arow) * 32 + ak4];
    float wv[32];
#pragma unroll
    for (int j = 0; j < 32; j++) wv[j] = Wfc[(kc * 32 + j) * 256 + tid];
    __syncthreads();
    *(ushort4*)&As[arow][ak4] = av;
    {
      __hip_bfloat16 tw[32];
#pragma unroll
      for (int j = 0; j < 32; j++) tw[j] = __float2bfloat16(wv[j]);
#pragma unroll
      for (int g = 0; g < 4; g++) *(uint4*)&Bs[tid][g * 8] = *(uint4*)&tw[g * 8];
    }
    __syncthreads();
    bfrag8 aA[2], bB[4];
#pragma unroll
    for (int t = 0; t < 2; t++)
      aA[t] = *(const bfrag8*)&As[t * 16 + cl][quad * 8];
#pragma unroll
    for (int u = 0; u < 4; u++)
      bB[u] = *(const bfrag8*)&Bs[w * 64 + u * 16 + cl][quad * 8];
#pragma unroll
    for (int t = 0; t < 2; t++)
#pragma unroll
      for (int u = 0; u < 4; u++)
        acc[t][u] =
            __builtin_amdgcn_mfma_f32_16x16x32_bf16(aA[t], bB[u], acc[t][u], 0, 0, 0);
  }

#pragma unroll
  for (int t = 0; t < 2; t++)
#pragma unroll
    for (int u = 0; u < 4; u++)
#pragma unroll
      for (int reg = 0; reg < 4; reg++)
        xs[t * 16 + quad * 4 + reg][w * 64 + u * 16 + cl] = acc[t][u][reg];
  __syncthreads();

  {
    int r = tid >> 3, c0 = (tid & 7) * 32;
    float s1 = 0.f, s2 = 0.f;
    for (int j = 0; j < 32; j += 4) {
      float4 v = *(const float4*)&xs[r][c0 + j];
      s1 += v.x + v.y + v.z + v.w;
      s2 += v.x * v.x + v.y * v.y + v.z * v.z + v.w * v.w;
    }
    red2[r][tid & 7][0] = s1;
    red2[r][tid & 7][1] = s2;
  }
  __syncthreads();
  if (tid < 32) {
    float s1 = 0.f, s2 = 0.f;
#pragma unroll
    for (int j = 0; j < 8; j++) {
      s1 += red2[tid][j][0];
      s2 += red2[tid][j][1];
    }
    float mu = s1 * (1.f / 256.f);
    float var = s2 * (1.f / 256.f) - mu * mu;
    musig[tid][0] = mu;
    musig[tid][1] = rsqrtf(var + 1e-5f);
  }
  __syncthreads();
  {
    float gt = lng[tid], bt = lnb[tid];
#pragma unroll 4
    for (int r = 0; r < 32; r++)
      out[(m0 + r) * 256 + tid] =
          gt * (xs[r][tid] - musig[r][0]) * musig[r][1] + bt;
  }
}

// ---------------------------------------------------------------------------
extern "C" void kernel_launch(void* const* d_in, const int* in_sizes, int n_in,
                              void* d_out, int out_size, void* d_ws,
                              size_t ws_size, hipStream_t stream) {
  const float* inQ = (const float*)d_in[0];
  const float* inK = (const float*)d_in[1];
  const float* inV = (const float*)d_in[2];
  const void* mask = d_in[3];
  const float* matrix = (const float*)d_in[4];
  const float* Wq = (const float*)d_in[5];
  const float* Wk = (const float*)d_in[6];
  const float* Wv = (const float*)d_in[7];
  const float* Wv2 = (const float*)d_in[8];
  const float* Wfc = (const float*)d_in[9];
  const float* lng = (const float*)d_in[10];
  const float* lnb = (const float*)d_in[11];
  const float* fulng = (const float*)d_in[12];
  const float* fulnb = (const float*)d_in[13];
  const float* fuw1 = (const float*)d_in[14];
  const float* fub1 = (const float*)d_in[15];
  const float* fuw2 = (const float*)d_in[16];
  const float* fub2 = (const float*)d_in[17];

  float* ws = (float*)d_ws;
  __hip_bfloat16* Qb = (__hip_bfloat16*)(ws + OFF_QB);
  __hip_bfloat16* Kb = (__hip_bfloat16*)(ws + OFF_KB);
  __hip_bfloat16* Vt = (__hip_bfloat16*)(ws + OFF_VT);
  float* Vp2 = ws + OFF_VP2;
  __hip_bfloat16* ctxb = (__hip_bfloat16*)(ws + OFF_CTXB);
  __hip_bfloat16* ctx2b = (__hip_bfloat16*)(ws + OFF_CTX2B);
  __hip_bfloat16* gws = (__hip_bfloat16*)(ws + OFF_G);
  unsigned int* flag = (unsigned int*)(ws + OFF_FLAG);

  float* out = (float*)d_out;
  float* mout = out + BB * SS * DM;

  hipMemsetAsync(flag, 0, 4, stream);
  mask_or_kernel<<<64, 256, 0, stream>>>((const unsigned int*)mask, flag);
  gemm_qkv_kernel<<<1536, 256, 0, stream>>>(inQ, inK, inV, Wq, Wk, Wv, Qb, Kb,
                                            Vt);
  vp2_kernel<<<512, 256, 0, stream>>>(inV, Wv2, Vp2);
  attn_kernel<<<512, 512, 0, stream>>>(Qb, Kb, Vt, mask, matrix, fulng, fulnb,
                                       fuw1, fub1, fuw2, fub2, ctxb, gws, flag);
  mout_kernel<<<BB * 64, 256, 0, stream>>>(matrix, gws, mout);
  ctx2_kernel<<<512, 256, 0, stream>>>(matrix, Vp2, ctx2b);
  final_kernel<<<256, 256, 0, stream>>>(ctxb, ctx2b, Wfc, lng, lnb, out);
}